// Round 13
// baseline (629.683 us; speedup 1.0000x reference)
//
#include <hip/hip_runtime.h>
#include <hip/hip_bf16.h>

#define B_   16
#define C_   512
#define N_   1024
#define NTOK 16384
#define SCALE_ 0.17677669529663687f
#define EPS_ 1e-5f

typedef __attribute__((ext_vector_type(8))) short bf16x8;
typedef __attribute__((ext_vector_type(4))) float f32x4;
typedef __attribute__((ext_vector_type(4))) short sh4;

#define GLOBAL_AS __attribute__((address_space(1)))
#define LDS_AS    __attribute__((address_space(3)))
#define MFMA16 __builtin_amdgcn_mfma_f32_16x16x32_bf16

__device__ __forceinline__ short f2bs(float v){
    __hip_bfloat16 h = __float2bfloat16(v);
    return *reinterpret_cast<short*>(&h);
}
__device__ __forceinline__ float bs2f(short s){
    __hip_bfloat16 h = *reinterpret_cast<__hip_bfloat16*>(&s);
    return __bfloat162float(h);
}
__device__ __forceinline__ void gload16(const void* g, void* l){
    __builtin_amdgcn_global_load_lds((const GLOBAL_AS unsigned int*)g,
                                     (LDS_AS unsigned int*)l, 16, 0, 0);
}

enum { AG_ROW = 0, AG_POOL = 1, AG_FUSE = 2, AG_CONV = 3, AG_SEL3 = 4, AG_QK = 5,
       AG_ROWF = 6, AG_POOLF = 7 };
enum { EP_QKV = 0, EP_POOL = 1, EP_PVN = 7, EP_FUSE_STATS = 8, EP_SPLIT_F32 = 9, EP_SCOREP = 10 };
enum { ORD_INNER_N = 0, ORD_INNER_M = 1 };

// ------------------------------------------------------------------ utility kernels
__global__ __launch_bounds__(256) void k_zero(float* p, int n){
    int i = blockIdx.x*256 + threadIdx.x;
    if (i < n) p[i] = 0.f;
}

__global__ __launch_bounds__(256) void k_cast(const float* __restrict__ s, short* __restrict__ d, int n){
    int i = (blockIdx.x*256 + threadIdx.x)*4;
    if (i >= n) return;
    float4 v = *reinterpret_cast<const float4*>(s + i);
    sh4 o; o[0]=f2bs(v.x); o[1]=f2bs(v.y); o[2]=f2bs(v.z); o[3]=f2bs(v.w);
    *reinterpret_cast<sh4*>(d + i) = o;
}

// transpose-cast: src fp32 [R][Cc] -> dst bf16 [Cc][R]
__global__ __launch_bounds__(256) void k_tcast(const float* __restrict__ src, short* __restrict__ dst,
                                               int R, int Cc){
    __shared__ float t[32][33];
    int bx = blockIdx.x*32, by = blockIdx.y*32;
    int tx = threadIdx.x & 31, ty = threadIdx.x >> 5;
    #pragma unroll
    for (int i = 0; i < 32; i += 8)
        t[ty+i][tx] = src[(size_t)(by+ty+i)*Cc + bx+tx];
    __syncthreads();
    #pragma unroll
    for (int i = 0; i < 32; i += 8)
        dst[(size_t)(bx+ty+i)*R + by+tx] = f2bs(t[tx][ty+i]);
}

// ------------------------------------------------------------------ MFMA GEMM template
// C[m][n] = sum_k A[m][k]*Bt[n][k]; 128x128 tile, BK=32, 4 waves, single-buffer (m97)
// AG_ROWF/AG_POOLF: A is fp32 in global, staged fp32 to LDS, converted bf16 at frag read.
template<int AM, int EP, int ORDER, int NX, int NY, int NZ, int NT, int KT, int KROW, int KSPLIT,
         long ASTR, long BSTR>
__global__ __launch_bounds__(256) void k_mm(const short* __restrict__ A,
                                            const short* __restrict__ Bt,
                                            const short* __restrict__ A2,
                                            const float* __restrict__ sc0,
                                            void* __restrict__ O0,
                                            void* __restrict__ O1,
                                            void* __restrict__ O2,
                                            void* __restrict__ O3){
    constexpr bool AF32 = (AM == AG_ROWF || AM == AG_POOLF);
    __shared__ short Asm[AF32 ? 128*64 : 128*32];
    __shared__ short Bsm[128*32];
    const int tid = threadIdx.x, wave = tid >> 6, lane = tid & 63;

    // ---- chunked XCD swizzle (bijective) ----
    constexpr int nwg = NX*NY*NZ;
    constexpr int q8 = nwg >> 3, r8 = nwg & 7;
    int orig = blockIdx.x;
    int xcd = orig & 7, idx8 = orig >> 3;
    int wg = (xcd < r8 ? xcd*(q8+1) : r8*(q8+1) + (xcd - r8)*q8) + idx8;
    int bz = wg / (NX*NY);
    int rem = wg - bz*(NX*NY);
    int nx, my;
    if constexpr (ORDER == ORD_INNER_N){ my = rem / NX; nx = rem - my*NX; }
    else                               { nx = rem / NY; my = rem - nx*NY; }

    const int m0 = my*128, n0 = nx*128;
    const short* Ab;
    if constexpr (AM == AG_SEL3){
        const short* base = (bz < 16) ? A : (bz < 32) ? A2 : (const short*)O3;
        Ab = base + (size_t)(bz & 15)*ASTR;
    } else if constexpr (AM == AG_QK){
        Ab = A + (size_t)(bz & 15)*ASTR;
    } else {
        Ab = A + (size_t)bz*ASTR;
    }
    const short* Bb;
    if constexpr (AM == AG_QK){
        const short* bbase = (bz < 16) ? Bt : (bz < 32) ? A2 : (const short*)O3;
        Bb = bbase + (size_t)(bz & 15)*BSTR;
    } else {
        Bb = Bt + (size_t)bz*BSTR;
    }

    f32x4 acc[4][4];
    #pragma unroll
    for (int i = 0; i < 4; ++i)
        #pragma unroll
        for (int j = 0; j < 4; ++j)
            acc[i][j] = (f32x4){0.f,0.f,0.f,0.f};

    const int wm = (wave >> 1)*64, wn = (wave & 1)*64;
    const int lrow = lane & 15, lk = (lane >> 4)*8;

    for (int k0 = 0; k0 < KT; k0 += 32){
        if constexpr (AF32){
            const float* Afp = (const float*)A;
            #pragma unroll
            for (int is = 0; is < 4; ++is){
                int fl = is*256 + tid;
                int r = fl >> 3, c4 = (fl & 7)*4;
                const float* gaf;
                if constexpr (AM == AG_ROWF){
                    gaf = Afp + (size_t)(m0 + r)*KROW + k0 + c4;
                } else { // AG_POOLF
                    int m = m0 + r;
                    int b = m >> 12, rem2 = m & 4095, g = rem2 >> 2, qd = rem2 & 3;
                    int srow = (b*64 + (g>>5)*2 + (qd>>1))*64 + (g&31)*2 + (qd&1);
                    gaf = Afp + (size_t)srow*KROW + k0 + c4;
                }
                gload16(gaf, &Asm[(is*256 + wave*64)*8]);
            }
            #pragma unroll
            for (int is = 0; is < 2; ++is){
                int fl = is*256 + tid;
                int r = fl >> 2, ccol = (fl & 3)*8;
                const short* gb = Bb + (size_t)(n0 + r)*KROW + k0 + ccol;
                gload16(gb, &Bsm[(is*4 + wave)*512]);
            }
        } else {
            #pragma unroll
            for (int is = 0; is < 2; ++is){
                int fl = is*256 + tid;
                int r = fl >> 2, ccol = (fl & 3)*8;
                int kk = bz*KSPLIT + k0 + ccol;
                const short* ga;
                if constexpr (AM == AG_ROW || AM == AG_SEL3 || AM == AG_QK){
                    ga = Ab + (size_t)(m0 + r)*KROW + kk;
                } else if constexpr (AM == AG_POOL){
                    int m = m0 + r;
                    int b = m >> 12, rem2 = m & 4095, g = rem2 >> 2, qd = rem2 & 3;
                    int srow = (b*64 + (g>>5)*2 + (qd>>1))*64 + (g&31)*2 + (qd&1);
                    ga = Ab + (size_t)srow*KROW + kk;
                } else if constexpr (AM == AG_FUSE){
                    int m = m0 + r;
                    int b = m >> 10, rem2 = m & 1023, h = rem2 >> 5, w = rem2 & 31;
                    const short* src = (kk < 512) ? A : A2;
                    ga = src + ((size_t)(b*512 + h*16 + (w>>1))*1024 + ((w&1)<<9) + (kk & 511));
                } else { // AG_CONV
                    int m = m0 + r;
                    int b = m >> 10, rem2 = m & 1023, h = rem2 >> 5, w = rem2 & 31;
                    int tap = kk >> 9, ic = kk & 511;
                    int dh = tap/3 - 1, dw = tap - (tap/3)*3 - 1;
                    int hs = h + dh, wd = w + dw;
                    if (hs >= 0 && hs < 32 && wd >= 0 && wd < 32)
                        ga = A + ((size_t)((b*32 + hs)*32 + wd)*512 + ic);
                    else
                        ga = A2;                 // zero page
                }
                gload16(ga, &Asm[(is*4 + wave)*512]);
                const short* gb = Bb + (size_t)(n0 + r)*KROW + kk;
                gload16(gb, &Bsm[(is*4 + wave)*512]);
            }
        }
        __syncthreads();
        bf16x8 af[4], bfr[4];
        if constexpr (AF32){
            const float* Afl = (const float*)Asm;
            #pragma unroll
            for (int mi = 0; mi < 4; ++mi){
                int rr = wm + mi*16 + lrow;
                float4 u0 = *(const float4*)&Afl[rr*32 + lk];
                float4 u1 = *(const float4*)&Afl[rr*32 + lk + 4];
                bf16x8 a;
                a[0]=f2bs(u0.x); a[1]=f2bs(u0.y); a[2]=f2bs(u0.z); a[3]=f2bs(u0.w);
                a[4]=f2bs(u1.x); a[5]=f2bs(u1.y); a[6]=f2bs(u1.z); a[7]=f2bs(u1.w);
                af[mi] = a;
            }
        } else {
            #pragma unroll
            for (int mi = 0; mi < 4; ++mi)
                af[mi] = *(const bf16x8*)&Asm[(wm + mi*16 + lrow)*32 + lk];
        }
        #pragma unroll
        for (int nj = 0; nj < 4; ++nj)
            bfr[nj] = *(const bf16x8*)&Bsm[(wn + nj*16 + lrow)*32 + lk];
        #pragma unroll
        for (int mi = 0; mi < 4; ++mi)
            #pragma unroll
            for (int nj = 0; nj < 4; ++nj)
                acc[mi][nj] = MFMA16(af[mi], bfr[nj], acc[mi][nj], 0, 0, 0);
        __syncthreads();
    }

    // ---------------- epilogue: C/D layout col=lane&15, row=(lane>>4)*4+reg
    const int lg = lane >> 4;

    if constexpr (EP == EP_FUSE_STATS){
        // bf16 store + per-block BN stats (LDS reduce over the 128x128 tile -> atomics)
        float* redS = (float*)Asm;   // [128][8]
        float* redQ = (float*)Bsm;   // [128][8]
        #pragma unroll
        for (int nj = 0; nj < 4; ++nj){
            int c = n0 + wn + nj*16 + lrow;
            float bias = sc0[c];
            float s = 0.f, qq = 0.f;
            #pragma unroll
            for (int mi = 0; mi < 4; ++mi){
                int r0 = m0 + wm + mi*16 + lg*4;
                #pragma unroll
                for (int rg = 0; rg < 4; ++rg){
                    float val = acc[mi][nj][rg] + bias;
                    s += val; qq += val*val;
                    ((short*)O0)[(size_t)(r0+rg)*NT + c] = f2bs(val);
                }
            }
            int chl = wn + nj*16 + lrow;
            int slot = (wave >> 1)*4 + lg;
            redS[chl*8 + slot] = s;
            redQ[chl*8 + slot] = qq;
        }
        __syncthreads();
        if (tid < 128){
            float S = 0.f, Q = 0.f;
            #pragma unroll
            for (int k = 0; k < 8; ++k){ S += redS[tid*8 + k]; Q += redQ[tid*8 + k]; }
            atomicAdd(&((float*)O1)[n0 + tid], S);
            atomicAdd(&((float*)O2)[n0 + tid], Q);
        }
        return;
    }

    if constexpr (EP == EP_SCOREP){
        // P = exp(s*SCALE) bf16 store + row-sum partials -> atomicAdd lsum[bz][row]
        short* Pb = (short*)O0 + ((size_t)bz << 20);
        float* lsum = (float*)O1 + (size_t)bz*1024;
        #pragma unroll
        for (int mi = 0; mi < 4; ++mi){
            int r0 = m0 + wm + mi*16 + lg*4;
            float s4[4] = {0.f, 0.f, 0.f, 0.f};
            #pragma unroll
            for (int nj = 0; nj < 4; ++nj){
                int c = n0 + wn + nj*16 + lrow;
                f32x4 v = acc[mi][nj];
                #pragma unroll
                for (int rg = 0; rg < 4; ++rg){
                    float p = __expf(fminf(v[rg]*SCALE_, 80.f));
                    s4[rg] += p;
                    Pb[(size_t)(r0+rg)*NT + c] = f2bs(p);
                }
            }
            #pragma unroll
            for (int off = 1; off < 16; off <<= 1){
                #pragma unroll
                for (int rg = 0; rg < 4; ++rg) s4[rg] += __shfl_xor(s4[rg], off);
            }
            if (lrow == 0){
                #pragma unroll
                for (int rg = 0; rg < 4; ++rg) atomicAdd(&lsum[r0+rg], s4[rg]);
            }
        }
        return;
    }

    #pragma unroll
    for (int mi = 0; mi < 4; ++mi)
        #pragma unroll
        for (int nj = 0; nj < 4; ++nj){
            int c  = n0 + wn + nj*16 + lrow;
            int r0 = m0 + wm + mi*16 + lg*4;
            f32x4 v = acc[mi][nj];
            if constexpr (EP == EP_QKV){
                sh4 t4;
                #pragma unroll
                for (int rg = 0; rg < 4; ++rg){
                    short s = f2bs(v[rg]);
                    ((short*)O0)[(size_t)(r0+rg)*NT + c] = s;
                    t4[rg] = s;
                }
                int b = r0 >> 10, t = r0 & 1023;
                *reinterpret_cast<sh4*>((short*)O1 + ((size_t)(b*512 + c))*1024 + t) = t4;
            } else if constexpr (EP == EP_POOL){
                float av = 0.25f*(v[0]+v[1]+v[2]+v[3]);
                float mx = fmaxf(fmaxf(v[0],v[1]), fmaxf(v[2],v[3]));
                int g = r0 >> 2;
                int b = g >> 10, t = g & 1023;
                ((short*)O0)[(size_t)g*512 + c] = f2bs(av);
                ((short*)O2)[(size_t)g*512 + c] = f2bs(mx);
                ((short*)O1)[((size_t)(b*512 + c))*1024 + t] = f2bs(av);
                ((short*)O3)[((size_t)(b*512 + c))*1024 + t] = f2bs(mx);
            } else if constexpr (EP == EP_PVN){
                short* Ob = ((bz < 16) ? (short*)O0 : (bz < 32) ? (short*)O1 : (short*)O2)
                            + (size_t)(bz & 15)*524288;
                float sc = 1.f / sc0[(size_t)bz*1024 + c];
                #pragma unroll
                for (int rg = 0; rg < 4; ++rg)
                    Ob[(size_t)(r0+rg)*NT + c] = f2bs(v[rg]*sc);
            } else { // EP_SPLIT_F32
                float* O = (float*)O0 + (size_t)bz*((long)NTOK*NT);
                #pragma unroll
                for (int rg = 0; rg < 4; ++rg)
                    O[(size_t)(r0+rg)*NT + c] = v[rg];
            }
        }
}

// ------------------------------------------------------------------ x_prev^T = beta*avgT + (1-beta)*maxT
__global__ __launch_bounds__(256) void k_combine(const short* __restrict__ av,
                                                 const short* __restrict__ mx,
                                                 short* __restrict__ o,
                                                 const float* __restrict__ beta){
    int i = (blockIdx.x*256 + threadIdx.x)*8;
    float be = beta[0];
    bf16x8 va = *(const bf16x8*)&av[i];
    bf16x8 vm = *(const bf16x8*)&mx[i];
    bf16x8 vo;
    #pragma unroll
    for (int j = 0; j < 8; ++j)
        vo[j] = f2bs(be*bs2f(va[j]) + (1.f - be)*bs2f(vm[j]));
    *reinterpret_cast<bf16x8*>(&o[i]) = vo;
}

// ------------------------------------------------------------------ merge fp32 split-K conv partials + bias,
// write fp32 Y, accumulate BN2 stats (float4 vectorized)
__global__ __launch_bounds__(256) void k_stats2(const float* __restrict__ p0,
                                                const float* __restrict__ p1,
                                                const float* __restrict__ bias,
                                                float* __restrict__ Y,
                                                float* __restrict__ sum, float* __restrict__ sumsq){
    int t = threadIdx.x;
    int c0 = (t & 127)*4;
    int r0 = blockIdx.x*32 + (t >> 7)*16;
    float4 bz4 = *reinterpret_cast<const float4*>(bias + c0);
    float s[4] = {0,0,0,0}, q[4] = {0,0,0,0};
    for (int r = 0; r < 16; ++r){
        size_t off = (size_t)(r0 + r)*C_ + c0;
        float4 a = *reinterpret_cast<const float4*>(p0 + off);
        float4 b = *reinterpret_cast<const float4*>(p1 + off);
        float v0 = a.x + b.x + bz4.x, v1 = a.y + b.y + bz4.y;
        float v2 = a.z + b.z + bz4.z, v3 = a.w + b.w + bz4.w;
        float4 ov = make_float4(v0, v1, v2, v3);
        *reinterpret_cast<float4*>(Y + off) = ov;
        s[0]+=v0; q[0]+=v0*v0; s[1]+=v1; q[1]+=v1*v1;
        s[2]+=v2; q[2]+=v2*v2; s[3]+=v3; q[3]+=v3*v3;
    }
    #pragma unroll
    for (int j = 0; j < 4; ++j){
        atomicAdd(&sum[c0+j],   s[j]);
        atomicAdd(&sumsq[c0+j], q[j]);
    }
}

// ------------------------------------------------------------------ x2 = x + gamma*relu(BN1(fusx)), bf16 in/out, x4
__global__ __launch_bounds__(256) void k_apply1(const short* __restrict__ fusxq,
                                                const float* __restrict__ x,
                                                const float* __restrict__ sum,
                                                const float* __restrict__ sumsq,
                                                const float* __restrict__ g,
                                                const float* __restrict__ bb,
                                                const float* __restrict__ gamma,
                                                short* __restrict__ x2q){
    int i4 = (blockIdx.x*256 + threadIdx.x)*4;
    int c = i4 & (C_-1);
    sh4 f = *reinterpret_cast<const sh4*>(fusxq + i4);
    float4 xv = *reinterpret_cast<const float4*>(x + i4);
    float gm = gamma[0];
    sh4 o;
    #pragma unroll
    for (int j = 0; j < 4; ++j){
        int cj = c + j;
        float mean = sum[cj]*(1.f/NTOK);
        float var  = sumsq[cj]*(1.f/NTOK) - mean*mean;
        float t = (bs2f(f[j]) - mean)*rsqrtf(var + EPS_)*g[cj] + bb[cj];
        float xj = (j==0) ? xv.x : (j==1) ? xv.y : (j==2) ? xv.z : xv.w;
        o[j] = f2bs(xj + gm*fmaxf(t, 0.f));
    }
    *reinterpret_cast<sh4*>(x2q + i4) = o;
}

// ------------------------------------------------------------------ out = relu(BN2(y)) in place, float4
__global__ __launch_bounds__(256) void k_apply2(float* __restrict__ Y,
                                                const float* __restrict__ sum,
                                                const float* __restrict__ sumsq,
                                                const float* __restrict__ g,
                                                const float* __restrict__ bb){
    int i4 = (blockIdx.x*256 + threadIdx.x)*4;
    int c = i4 & (C_-1);
    float4 v = *reinterpret_cast<float4*>(Y + i4);
    float o[4] = {v.x, v.y, v.z, v.w};
    #pragma unroll
    for (int j = 0; j < 4; ++j){
        int cj = c + j;
        float mean = sum[cj]*(1.f/NTOK);
        float var  = sumsq[cj]*(1.f/NTOK) - mean*mean;
        float t = (o[j] - mean)*rsqrtf(var + EPS_)*g[cj] + bb[cj];
        o[j] = fmaxf(t, 0.f);
    }
    float4 ov; ov.x = o[0]; ov.y = o[1]; ov.z = o[2]; ov.w = o[3];
    *reinterpret_cast<float4*>(Y + i4) = ov;
}

// ------------------------------------------------------------------ launch
extern "C" void kernel_launch(void* const* d_in, const int* in_sizes, int n_in,
                              void* d_out, int out_size, void* d_ws, size_t ws_size,
                              hipStream_t stream){
    const float* x      = (const float*)d_in[0];
    const float* prevx  = (const float*)d_in[1];
    const float* w_prev = (const float*)d_in[2];
    const float* w_qkv  = (const float*)d_in[3];
    const float* fuse_w = (const float*)d_in[4];
    const float* fuse_b = (const float*)d_in[5];
    const float* bn1_g  = (const float*)d_in[6];
    const float* bn1_b  = (const float*)d_in[7];
    const float* out_w  = (const float*)d_in[8];
    const float* out_b  = (const float*)d_in[9];
    const float* bn2_g  = (const float*)d_in[10];
    const float* bn2_b  = (const float*)d_in[11];
    const float* gamma  = (const float*)d_in[12];
    const float* beta   = (const float*)d_in[13];
    float* out = (float*)d_out;

    char* ws8 = (char*)d_ws;
    // Phase-aliased region 0..100663296 (96 MiB):
    //   mid:   Pall bf16 [3][16][1024][1024]          [dead after PV GEMM]
    //   late:  cpart (2x33.6M fp32 conv split-K partials)
    short* Pall = (short*)(ws8 + 0);
    float* cpart= (float*)(ws8 + 0);
    short* qkvT = (short*)(ws8 + 100663296);
    short* x2q  = (short*)(ws8 + 100663296);     // alias: qkvT dead after PV
    short* avgkT= (short*)(ws8 + 117440512);
    short* maxkT= (short*)(ws8 + 134217728);
    short* prevT= maxkT;                         // combine writes after PV (maxkT dead)
    short* nowT = (short*)(ws8 + 150994944);
    short* avgk = nowT;                          // pool writes, scorep reads, PV overwrites
    short* avgT = (short*)(ws8 + 167772160);
    short* maxk = avgT;                          // pool writes, scorep reads, PV overwrites
    short* maxT = (short*)(ws8 + 184549376);
    short* fusxq= (short*)(ws8 + 184549376);     // bf16 fusx, aliases maxT after combine
    short* qkv  = (short*)(ws8 + 201326592);     // dead after scorep GEMM
    short* wqT  = (short*)(ws8 + 218103808);
    short* wpT  = (short*)(ws8 + 218628096);
    short* wfT  = (short*)(ws8 + 218890240);
    short* wcT  = (short*)(ws8 + 219938816);
    float* st   = (float*)(ws8 + 224657408);     // 2048 stats + 256-float zero page + lsum (contiguous)
    short* zpg  = (short*)(ws8 + 224665600);
    float* lsum = (float*)(ws8 + 224666624);     // 48*1024 f32 row sums
    float *s1sum = st, *s1sq = st + 512, *s2sum = st + 1024, *s2sq = st + 1536;

    dim3 blk(256);
    // zero: stats (2048) + zero page (256) + lsum (49152) — contiguous 51456 floats
    k_zero<<<201, blk, 0, stream>>>(st, 51456);
    // weight casts / transposes (x and prevx casts are fused into their GEMMs)
    k_cast<<<256,  blk, 0, stream>>>(w_qkv, wqT, 262144);
    k_cast<<<128,  blk, 0, stream>>>(w_prev, wpT, 131072);
    k_tcast<<<dim3(16, 32),  blk, 0, stream>>>(fuse_w, wfT, 1024, 512);
    k_tcast<<<dim3(16, 144), blk, 0, stream>>>(out_w, wcT, 4608, 512);

    // qkv = x @ w_qkv^T  (A = fp32 x staged directly; row-major + transposed out)
    k_mm<AG_ROWF, EP_QKV, ORD_INNER_N, 4, 128, 1, 512, 512, 512, 0, 0L, 0L>
        <<<512, blk, 0, stream>>>((const short*)x, wqT, nullptr, nullptr,
                                  qkv, qkvT, nullptr, nullptr);
    // prev qkv + fused 2x2 pooling (A = fp32 prevx staged directly)
    k_mm<AG_POOLF, EP_POOL, ORD_INNER_N, 4, 512, 1, 512, 256, 256, 0, 0L, 0L>
        <<<2048, blk, 0, stream>>>((const short*)prevx, wpT, nullptr, nullptr,
                                   avgk, avgkT, maxk, maxkT);
    // scores + no-max softmax as batched GEMM: P = exp(Q.K^T*SCALE) bf16, row sums -> lsum
    k_mm<AG_QK, EP_SCOREP, ORD_INNER_M, 8, 8, 48, 1024, 512, 512, 0, 524288L, 524288L>
        <<<3072, blk, 0, stream>>>(qkv, qkv, avgk, nullptr,
                                   Pall, lsum, nullptr, maxk);
    // PV as batched GEMM: O^T[ch][tok] = sum_kv V^T[ch][kv] * P[tok][kv], scaled by 1/lsum[tok]
    k_mm<AG_SEL3, EP_PVN, ORD_INNER_M, 8, 4, 48, 1024, 1024, 1024, 0, 524288L, 1048576L>
        <<<1536, blk, 0, stream>>>(qkvT, Pall, avgkT, lsum,
                                   nowT, avgT, maxT, maxkT);
    // x_prev^T = beta*avgT + (1-beta)*maxT
    k_combine<<<4096, blk, 0, stream>>>(avgT, maxT, prevT, beta);
    // fuse 1x1 + bias + BN1 stats fused into epilogue; fusx stored bf16
    k_mm<AG_FUSE, EP_FUSE_STATS, ORD_INNER_N, 4, 128, 1, 512, 1024, 1024, 0, 0L, 0L>
        <<<512, blk, 0, stream>>>(nowT, wfT, prevT, fuse_b,
                                  fusxq, s1sum, s1sq, nullptr);
    k_apply1<<<8192, blk, 0, stream>>>(fusxq, x, s1sum, s1sq, bn1_g, bn1_b, gamma, x2q);
    // 3x3 conv (implicit GEMM, split-K x2, fp32 partials) + merge/stats + BN2
    k_mm<AG_CONV, EP_SPLIT_F32, ORD_INNER_N, 4, 128, 2, 512, 2304, 4608, 2304, 0L, 0L>
        <<<1024, blk, 0, stream>>>(x2q, wcT, zpg, nullptr,
                                   cpart, nullptr, nullptr, nullptr);
    k_stats2<<<512, blk, 0, stream>>>(cpart, cpart + (size_t)NTOK*C_, out_b, out, s2sum, s2sq);
    k_apply2<<<8192, blk, 0, stream>>>(out, s2sum, s2sq, bn2_g, bn2_b);
}

// Round 14
// 545.013 us; speedup vs baseline: 1.1554x; 1.1554x over previous
//
#include <hip/hip_runtime.h>
#include <hip/hip_bf16.h>

#define B_   16
#define C_   512
#define N_   1024
#define NTOK 16384
#define SCALE_ 0.17677669529663687f
#define EPS_ 1e-5f

typedef __attribute__((ext_vector_type(8))) short bf16x8;
typedef __attribute__((ext_vector_type(4))) float f32x4;
typedef __attribute__((ext_vector_type(4))) short sh4;

#define GLOBAL_AS __attribute__((address_space(1)))
#define LDS_AS    __attribute__((address_space(3)))
#define MFMA16 __builtin_amdgcn_mfma_f32_16x16x32_bf16

__device__ __forceinline__ short f2bs(float v){
    __hip_bfloat16 h = __float2bfloat16(v);
    return *reinterpret_cast<short*>(&h);
}
__device__ __forceinline__ float bs2f(short s){
    __hip_bfloat16 h = *reinterpret_cast<__hip_bfloat16*>(&s);
    return __bfloat162float(h);
}
__device__ __forceinline__ void gload16(const void* g, void* l){
    __builtin_amdgcn_global_load_lds((const GLOBAL_AS unsigned int*)g,
                                     (LDS_AS unsigned int*)l, 16, 0, 0);
}

enum { AG_ROW = 0, AG_POOL = 1, AG_FUSE = 2, AG_CONV = 3, AG_SEL3 = 4, AG_QK = 5 };
enum { EP_QKV = 0, EP_POOL = 1, EP_PVN = 7, EP_FUSE_STATS = 8, EP_SPLIT_F32 = 9, EP_SCOREP = 10 };
enum { ORD_INNER_N = 0, ORD_INNER_M = 1 };

// ------------------------------------------------------------------ utility kernels
__global__ __launch_bounds__(256) void k_zero(float* p, int n){
    int i = blockIdx.x*256 + threadIdx.x;
    if (i < n) p[i] = 0.f;
}

__global__ __launch_bounds__(256) void k_cast(const float* __restrict__ s, short* __restrict__ d, int n){
    int i = (blockIdx.x*256 + threadIdx.x)*4;
    if (i >= n) return;
    float4 v = *reinterpret_cast<const float4*>(s + i);
    sh4 o; o[0]=f2bs(v.x); o[1]=f2bs(v.y); o[2]=f2bs(v.z); o[3]=f2bs(v.w);
    *reinterpret_cast<sh4*>(d + i) = o;
}

// transpose-cast: src fp32 [R][Cc] -> dst bf16 [Cc][R]
__global__ __launch_bounds__(256) void k_tcast(const float* __restrict__ src, short* __restrict__ dst,
                                               int R, int Cc){
    __shared__ float t[32][33];
    int bx = blockIdx.x*32, by = blockIdx.y*32;
    int tx = threadIdx.x & 31, ty = threadIdx.x >> 5;
    #pragma unroll
    for (int i = 0; i < 32; i += 8)
        t[ty+i][tx] = src[(size_t)(by+ty+i)*Cc + bx+tx];
    __syncthreads();
    #pragma unroll
    for (int i = 0; i < 32; i += 8)
        dst[(size_t)(bx+ty+i)*R + by+tx] = f2bs(t[tx][ty+i]);
}

// ------------------------------------------------------------------ MFMA GEMM template
// C[m][n] = sum_k A[m][k]*Bt[n][k]; 128x128 tile, BK=32, 4 waves, single-buffer (m97)
template<int AM, int EP, int ORDER, int NX, int NY, int NZ, int NT, int KT, int KROW, int KSPLIT,
         long ASTR, long BSTR>
__global__ __launch_bounds__(256) void k_mm(const short* __restrict__ A,
                                            const short* __restrict__ Bt,
                                            const short* __restrict__ A2,
                                            const float* __restrict__ sc0,
                                            void* __restrict__ O0,
                                            void* __restrict__ O1,
                                            void* __restrict__ O2,
                                            void* __restrict__ O3){
    __shared__ short Asm[128*32];
    __shared__ short Bsm[128*32];
    const int tid = threadIdx.x, wave = tid >> 6, lane = tid & 63;

    // ---- chunked XCD swizzle (bijective) ----
    constexpr int nwg = NX*NY*NZ;
    constexpr int q8 = nwg >> 3, r8 = nwg & 7;
    int orig = blockIdx.x;
    int xcd = orig & 7, idx8 = orig >> 3;
    int wg = (xcd < r8 ? xcd*(q8+1) : r8*(q8+1) + (xcd - r8)*q8) + idx8;
    int bz = wg / (NX*NY);
    int rem = wg - bz*(NX*NY);
    int nx, my;
    if constexpr (ORDER == ORD_INNER_N){ my = rem / NX; nx = rem - my*NX; }
    else                               { nx = rem / NY; my = rem - nx*NY; }

    const int m0 = my*128, n0 = nx*128;
    const short* Ab;
    if constexpr (AM == AG_SEL3){
        const short* base = (bz < 16) ? A : (bz < 32) ? A2 : (const short*)O3;
        Ab = base + (size_t)(bz & 15)*ASTR;
    } else if constexpr (AM == AG_QK){
        Ab = A + (size_t)(bz & 15)*ASTR;
    } else {
        Ab = A + (size_t)bz*ASTR;
    }
    const short* Bb;
    if constexpr (AM == AG_QK){
        const short* bbase = (bz < 16) ? Bt : (bz < 32) ? A2 : (const short*)O3;
        Bb = bbase + (size_t)(bz & 15)*BSTR;
    } else {
        Bb = Bt + (size_t)bz*BSTR;
    }

    f32x4 acc[4][4];
    #pragma unroll
    for (int i = 0; i < 4; ++i)
        #pragma unroll
        for (int j = 0; j < 4; ++j)
            acc[i][j] = (f32x4){0.f,0.f,0.f,0.f};

    const int wm = (wave >> 1)*64, wn = (wave & 1)*64;
    const int lrow = lane & 15, lk = (lane >> 4)*8;

    for (int k0 = 0; k0 < KT; k0 += 32){
        #pragma unroll
        for (int is = 0; is < 2; ++is){
            int fl = is*256 + tid;
            int r = fl >> 2, ccol = (fl & 3)*8;
            int kk = bz*KSPLIT + k0 + ccol;
            const short* ga;
            if constexpr (AM == AG_ROW || AM == AG_SEL3 || AM == AG_QK){
                ga = Ab + (size_t)(m0 + r)*KROW + kk;
            } else if constexpr (AM == AG_POOL){
                int m = m0 + r;
                int b = m >> 12, rem2 = m & 4095, g = rem2 >> 2, qd = rem2 & 3;
                int srow = (b*64 + (g>>5)*2 + (qd>>1))*64 + (g&31)*2 + (qd&1);
                ga = Ab + (size_t)srow*KROW + kk;
            } else if constexpr (AM == AG_FUSE){
                int m = m0 + r;
                int b = m >> 10, rem2 = m & 1023, h = rem2 >> 5, w = rem2 & 31;
                const short* src = (kk < 512) ? A : A2;
                ga = src + ((size_t)(b*512 + h*16 + (w>>1))*1024 + ((w&1)<<9) + (kk & 511));
            } else { // AG_CONV
                int m = m0 + r;
                int b = m >> 10, rem2 = m & 1023, h = rem2 >> 5, w = rem2 & 31;
                int tap = kk >> 9, ic = kk & 511;
                int dh = tap/3 - 1, dw = tap - (tap/3)*3 - 1;
                int hs = h + dh, wd = w + dw;
                if (hs >= 0 && hs < 32 && wd >= 0 && wd < 32)
                    ga = A + ((size_t)((b*32 + hs)*32 + wd)*512 + ic);
                else
                    ga = A2;                 // zero page
            }
            gload16(ga, &Asm[(is*4 + wave)*512]);
            const short* gb = Bb + (size_t)(n0 + r)*KROW + kk;
            gload16(gb, &Bsm[(is*4 + wave)*512]);
        }
        __syncthreads();
        bf16x8 af[4], bfr[4];
        #pragma unroll
        for (int mi = 0; mi < 4; ++mi)
            af[mi] = *(const bf16x8*)&Asm[(wm + mi*16 + lrow)*32 + lk];
        #pragma unroll
        for (int nj = 0; nj < 4; ++nj)
            bfr[nj] = *(const bf16x8*)&Bsm[(wn + nj*16 + lrow)*32 + lk];
        #pragma unroll
        for (int mi = 0; mi < 4; ++mi)
            #pragma unroll
            for (int nj = 0; nj < 4; ++nj)
                acc[mi][nj] = MFMA16(af[mi], bfr[nj], acc[mi][nj], 0, 0, 0);
        __syncthreads();
    }

    // ---------------- epilogue: C/D layout col=lane&15, row=(lane>>4)*4+reg
    const int lg = lane >> 4;

    if constexpr (EP == EP_FUSE_STATS){
        // bf16 store + per-block BN stats (LDS reduce over the 128x128 tile -> atomics)
        float* redS = (float*)Asm;   // [128][8]
        float* redQ = (float*)Bsm;   // [128][8]
        #pragma unroll
        for (int nj = 0; nj < 4; ++nj){
            int c = n0 + wn + nj*16 + lrow;
            float bias = sc0[c];
            float s = 0.f, qq = 0.f;
            #pragma unroll
            for (int mi = 0; mi < 4; ++mi){
                int r0 = m0 + wm + mi*16 + lg*4;
                #pragma unroll
                for (int rg = 0; rg < 4; ++rg){
                    float val = acc[mi][nj][rg] + bias;
                    s += val; qq += val*val;
                    ((short*)O0)[(size_t)(r0+rg)*NT + c] = f2bs(val);
                }
            }
            int chl = wn + nj*16 + lrow;
            int slot = (wave >> 1)*4 + lg;
            redS[chl*8 + slot] = s;
            redQ[chl*8 + slot] = qq;
        }
        __syncthreads();
        if (tid < 128){
            float S = 0.f, Q = 0.f;
            #pragma unroll
            for (int k = 0; k < 8; ++k){ S += redS[tid*8 + k]; Q += redQ[tid*8 + k]; }
            atomicAdd(&((float*)O1)[n0 + tid], S);
            atomicAdd(&((float*)O2)[n0 + tid], Q);
        }
        return;
    }

    if constexpr (EP == EP_SCOREP){
        // P = exp(s*SCALE) bf16 store + row-sum partials -> atomicAdd lsum[bz][row]
        short* Pb = (short*)O0 + ((size_t)bz << 20);
        float* lsum = (float*)O1 + (size_t)bz*1024;
        #pragma unroll
        for (int mi = 0; mi < 4; ++mi){
            int r0 = m0 + wm + mi*16 + lg*4;
            float s4[4] = {0.f, 0.f, 0.f, 0.f};
            #pragma unroll
            for (int nj = 0; nj < 4; ++nj){
                int c = n0 + wn + nj*16 + lrow;
                f32x4 v = acc[mi][nj];
                #pragma unroll
                for (int rg = 0; rg < 4; ++rg){
                    float p = __expf(fminf(v[rg]*SCALE_, 80.f));
                    s4[rg] += p;
                    Pb[(size_t)(r0+rg)*NT + c] = f2bs(p);
                }
            }
            #pragma unroll
            for (int off = 1; off < 16; off <<= 1){
                #pragma unroll
                for (int rg = 0; rg < 4; ++rg) s4[rg] += __shfl_xor(s4[rg], off);
            }
            if (lrow == 0){
                #pragma unroll
                for (int rg = 0; rg < 4; ++rg) atomicAdd(&lsum[r0+rg], s4[rg]);
            }
        }
        return;
    }

    #pragma unroll
    for (int mi = 0; mi < 4; ++mi)
        #pragma unroll
        for (int nj = 0; nj < 4; ++nj){
            int c  = n0 + wn + nj*16 + lrow;
            int r0 = m0 + wm + mi*16 + lg*4;
            f32x4 v = acc[mi][nj];
            if constexpr (EP == EP_QKV){
                sh4 t4;
                #pragma unroll
                for (int rg = 0; rg < 4; ++rg){
                    short s = f2bs(v[rg]);
                    ((short*)O0)[(size_t)(r0+rg)*NT + c] = s;
                    t4[rg] = s;
                }
                int b = r0 >> 10, t = r0 & 1023;
                *reinterpret_cast<sh4*>((short*)O1 + ((size_t)(b*512 + c))*1024 + t) = t4;
            } else if constexpr (EP == EP_POOL){
                float av = 0.25f*(v[0]+v[1]+v[2]+v[3]);
                float mx = fmaxf(fmaxf(v[0],v[1]), fmaxf(v[2],v[3]));
                int g = r0 >> 2;
                int b = g >> 10, t = g & 1023;
                ((short*)O0)[(size_t)g*512 + c] = f2bs(av);
                ((short*)O2)[(size_t)g*512 + c] = f2bs(mx);
                ((short*)O1)[((size_t)(b*512 + c))*1024 + t] = f2bs(av);
                ((short*)O3)[((size_t)(b*512 + c))*1024 + t] = f2bs(mx);
            } else if constexpr (EP == EP_PVN){
                short* Ob = ((bz < 16) ? (short*)O0 : (bz < 32) ? (short*)O1 : (short*)O2)
                            + (size_t)(bz & 15)*524288;
                float sc = 1.f / sc0[(size_t)bz*1024 + c];
                #pragma unroll
                for (int rg = 0; rg < 4; ++rg)
                    Ob[(size_t)(r0+rg)*NT + c] = f2bs(v[rg]*sc);
            } else { // EP_SPLIT_F32
                float* O = (float*)O0 + (size_t)bz*((long)NTOK*NT);
                #pragma unroll
                for (int rg = 0; rg < 4; ++rg)
                    O[(size_t)(r0+rg)*NT + c] = v[rg];
            }
        }
}

// ------------------------------------------------------------------ x_prev^T = beta*avgT + (1-beta)*maxT
__global__ __launch_bounds__(256) void k_combine(const short* __restrict__ av,
                                                 const short* __restrict__ mx,
                                                 short* __restrict__ o,
                                                 const float* __restrict__ beta){
    int i = (blockIdx.x*256 + threadIdx.x)*8;
    float be = beta[0];
    bf16x8 va = *(const bf16x8*)&av[i];
    bf16x8 vm = *(const bf16x8*)&mx[i];
    bf16x8 vo;
    #pragma unroll
    for (int j = 0; j < 8; ++j)
        vo[j] = f2bs(be*bs2f(va[j]) + (1.f - be)*bs2f(vm[j]));
    *reinterpret_cast<bf16x8*>(&o[i]) = vo;
}

// ------------------------------------------------------------------ merge fp32 split-K conv partials + bias,
// write fp32 Y, accumulate BN2 stats (float4 vectorized)
__global__ __launch_bounds__(256) void k_stats2(const float* __restrict__ p0,
                                                const float* __restrict__ p1,
                                                const float* __restrict__ bias,
                                                float* __restrict__ Y,
                                                float* __restrict__ sum, float* __restrict__ sumsq){
    int t = threadIdx.x;
    int c0 = (t & 127)*4;
    int r0 = blockIdx.x*32 + (t >> 7)*16;
    float4 bz4 = *reinterpret_cast<const float4*>(bias + c0);
    float s[4] = {0,0,0,0}, q[4] = {0,0,0,0};
    for (int r = 0; r < 16; ++r){
        size_t off = (size_t)(r0 + r)*C_ + c0;
        float4 a = *reinterpret_cast<const float4*>(p0 + off);
        float4 b = *reinterpret_cast<const float4*>(p1 + off);
        float v0 = a.x + b.x + bz4.x, v1 = a.y + b.y + bz4.y;
        float v2 = a.z + b.z + bz4.z, v3 = a.w + b.w + bz4.w;
        float4 ov = make_float4(v0, v1, v2, v3);
        *reinterpret_cast<float4*>(Y + off) = ov;
        s[0]+=v0; q[0]+=v0*v0; s[1]+=v1; q[1]+=v1*v1;
        s[2]+=v2; q[2]+=v2*v2; s[3]+=v3; q[3]+=v3*v3;
    }
    #pragma unroll
    for (int j = 0; j < 4; ++j){
        atomicAdd(&sum[c0+j],   s[j]);
        atomicAdd(&sumsq[c0+j], q[j]);
    }
}

// ------------------------------------------------------------------ x2 = x + gamma*relu(BN1(fusx)), bf16 in/out, x4
__global__ __launch_bounds__(256) void k_apply1(const short* __restrict__ fusxq,
                                                const float* __restrict__ x,
                                                const float* __restrict__ sum,
                                                const float* __restrict__ sumsq,
                                                const float* __restrict__ g,
                                                const float* __restrict__ bb,
                                                const float* __restrict__ gamma,
                                                short* __restrict__ x2q){
    int i4 = (blockIdx.x*256 + threadIdx.x)*4;
    int c = i4 & (C_-1);
    sh4 f = *reinterpret_cast<const sh4*>(fusxq + i4);
    float4 xv = *reinterpret_cast<const float4*>(x + i4);
    float gm = gamma[0];
    sh4 o;
    #pragma unroll
    for (int j = 0; j < 4; ++j){
        int cj = c + j;
        float mean = sum[cj]*(1.f/NTOK);
        float var  = sumsq[cj]*(1.f/NTOK) - mean*mean;
        float t = (bs2f(f[j]) - mean)*rsqrtf(var + EPS_)*g[cj] + bb[cj];
        float xj = (j==0) ? xv.x : (j==1) ? xv.y : (j==2) ? xv.z : xv.w;
        o[j] = f2bs(xj + gm*fmaxf(t, 0.f));
    }
    *reinterpret_cast<sh4*>(x2q + i4) = o;
}

// ------------------------------------------------------------------ out = relu(BN2(y)) in place, float4
__global__ __launch_bounds__(256) void k_apply2(float* __restrict__ Y,
                                                const float* __restrict__ sum,
                                                const float* __restrict__ sumsq,
                                                const float* __restrict__ g,
                                                const float* __restrict__ bb){
    int i4 = (blockIdx.x*256 + threadIdx.x)*4;
    int c = i4 & (C_-1);
    float4 v = *reinterpret_cast<float4*>(Y + i4);
    float o[4] = {v.x, v.y, v.z, v.w};
    #pragma unroll
    for (int j = 0; j < 4; ++j){
        int cj = c + j;
        float mean = sum[cj]*(1.f/NTOK);
        float var  = sumsq[cj]*(1.f/NTOK) - mean*mean;
        float t = (o[j] - mean)*rsqrtf(var + EPS_)*g[cj] + bb[cj];
        o[j] = fmaxf(t, 0.f);
    }
    float4 ov; ov.x = o[0]; ov.y = o[1]; ov.z = o[2]; ov.w = o[3];
    *reinterpret_cast<float4*>(Y + i4) = ov;
}

// ------------------------------------------------------------------ launch
extern "C" void kernel_launch(void* const* d_in, const int* in_sizes, int n_in,
                              void* d_out, int out_size, void* d_ws, size_t ws_size,
                              hipStream_t stream){
    const float* x      = (const float*)d_in[0];
    const float* prevx  = (const float*)d_in[1];
    const float* w_prev = (const float*)d_in[2];
    const float* w_qkv  = (const float*)d_in[3];
    const float* fuse_w = (const float*)d_in[4];
    const float* fuse_b = (const float*)d_in[5];
    const float* bn1_g  = (const float*)d_in[6];
    const float* bn1_b  = (const float*)d_in[7];
    const float* out_w  = (const float*)d_in[8];
    const float* out_b  = (const float*)d_in[9];
    const float* bn2_g  = (const float*)d_in[10];
    const float* bn2_b  = (const float*)d_in[11];
    const float* gamma  = (const float*)d_in[12];
    const float* beta   = (const float*)d_in[13];
    float* out = (float*)d_out;

    char* ws8 = (char*)d_ws;
    // Phase-aliased region 0..100663296 (96 MiB):
    //   early: pxq (33.5M @0), xq (16.8M @33554432)  [dead before scorep GEMM]
    //   mid:   Pall bf16 [3][16][1024][1024]          [dead after PV GEMM]
    //   late:  cpart (2x33.6M fp32 conv split-K partials)
    short* pxq  = (short*)(ws8 + 0);
    short* xq   = (short*)(ws8 + 33554432);
    short* Pall = (short*)(ws8 + 0);
    float* cpart= (float*)(ws8 + 0);
    short* qkvT = (short*)(ws8 + 100663296);
    short* x2q  = (short*)(ws8 + 100663296);     // alias: qkvT dead after PV
    short* avgkT= (short*)(ws8 + 117440512);
    short* maxkT= (short*)(ws8 + 134217728);
    short* prevT= maxkT;                         // combine writes after PV (maxkT dead)
    short* nowT = (short*)(ws8 + 150994944);
    short* avgk = nowT;                          // pool writes, scorep reads, PV overwrites
    short* avgT = (short*)(ws8 + 167772160);
    short* maxk = avgT;                          // pool writes, scorep reads, PV overwrites
    short* maxT = (short*)(ws8 + 184549376);
    short* fusxq= (short*)(ws8 + 184549376);     // bf16 fusx, aliases maxT after combine
    short* qkv  = (short*)(ws8 + 201326592);     // dead after scorep GEMM
    short* wqT  = (short*)(ws8 + 218103808);
    short* wpT  = (short*)(ws8 + 218628096);
    short* wfT  = (short*)(ws8 + 218890240);
    short* wcT  = (short*)(ws8 + 219938816);
    float* st   = (float*)(ws8 + 224657408);     // 2048 stats + 256-float zero page + lsum (contiguous)
    short* zpg  = (short*)(ws8 + 224665600);
    float* lsum = (float*)(ws8 + 224666624);     // 48*1024 f32 row sums
    float *s1sum = st, *s1sq = st + 512, *s2sum = st + 1024, *s2sq = st + 1536;

    dim3 blk(256);
    // zero: stats (2048) + zero page (256) + lsum (49152) — contiguous 51456 floats
    k_zero<<<201, blk, 0, stream>>>(st, 51456);
    // casts / weight transposes
    k_cast<<<8192, blk, 0, stream>>>(x, xq, 8388608);
    k_cast<<<256,  blk, 0, stream>>>(w_qkv, wqT, 262144);
    k_cast<<<128,  blk, 0, stream>>>(w_prev, wpT, 131072);
    k_tcast<<<dim3(16, 32),  blk, 0, stream>>>(fuse_w, wfT, 1024, 512);
    k_tcast<<<dim3(16, 144), blk, 0, stream>>>(out_w, wcT, 4608, 512);
    k_cast<<<16384, blk, 0, stream>>>(prevx, pxq, 16777216);

    // qkv = x @ w_qkv^T  (row-major + transposed out)
    k_mm<AG_ROW, EP_QKV, ORD_INNER_N, 4, 128, 1, 512, 512, 512, 0, 0L, 0L>
        <<<512, blk, 0, stream>>>(xq, wqT, nullptr, nullptr,
                                  qkv, qkvT, nullptr, nullptr);
    // prev qkv + fused 2x2 pooling (avgk/maxk row-major, avgkT/maxkT transposed)
    k_mm<AG_POOL, EP_POOL, ORD_INNER_N, 4, 512, 1, 512, 256, 256, 0, 0L, 0L>
        <<<2048, blk, 0, stream>>>(pxq, wpT, nullptr, nullptr,
                                   avgk, avgkT, maxk, maxkT);
    // scores + no-max softmax as batched GEMM: P = exp(Q.K^T*SCALE) bf16, row sums -> lsum
    k_mm<AG_QK, EP_SCOREP, ORD_INNER_M, 8, 8, 48, 1024, 512, 512, 0, 524288L, 524288L>
        <<<3072, blk, 0, stream>>>(qkv, qkv, avgk, nullptr,
                                   Pall, lsum, nullptr, maxk);
    // PV as batched GEMM: O^T[ch][tok] = sum_kv V^T[ch][kv] * P[tok][kv], scaled by 1/lsum[tok]
    k_mm<AG_SEL3, EP_PVN, ORD_INNER_M, 8, 4, 48, 1024, 1024, 1024, 0, 524288L, 1048576L>
        <<<1536, blk, 0, stream>>>(qkvT, Pall, avgkT, lsum,
                                   nowT, avgT, maxT, maxkT);
    // x_prev^T = beta*avgT + (1-beta)*maxT
    k_combine<<<4096, blk, 0, stream>>>(avgT, maxT, prevT, beta);
    // fuse 1x1 + bias + BN1 stats fused into epilogue; fusx stored bf16
    k_mm<AG_FUSE, EP_FUSE_STATS, ORD_INNER_N, 4, 128, 1, 512, 1024, 1024, 0, 0L, 0L>
        <<<512, blk, 0, stream>>>(nowT, wfT, prevT, fuse_b,
                                  fusxq, s1sum, s1sq, nullptr);
    k_apply1<<<8192, blk, 0, stream>>>(fusxq, x, s1sum, s1sq, bn1_g, bn1_b, gamma, x2q);
    // 3x3 conv (implicit GEMM, split-K x2, fp32 partials) + merge/stats + BN2
    k_mm<AG_CONV, EP_SPLIT_F32, ORD_INNER_N, 4, 128, 2, 512, 2304, 4608, 2304, 0L, 0L>
        <<<1024, blk, 0, stream>>>(x2q, wcT, zpg, nullptr,
                                   cpart, nullptr, nullptr, nullptr);
    k_stats2<<<512, blk, 0, stream>>>(cpart, cpart + (size_t)NTOK*C_, out_b, out, s2sum, s2sq);
    k_apply2<<<8192, blk, 0, stream>>>(out, s2sum, s2sq, bn2_g, bn2_b);
}

// Round 15
// 487.625 us; speedup vs baseline: 1.2913x; 1.1177x over previous
//
#include <hip/hip_runtime.h>
#include <hip/hip_bf16.h>

#define B_   16
#define C_   512
#define N_   1024
#define NTOK 16384
#define SCALE_ 0.17677669529663687f
#define EPS_ 1e-5f

typedef __attribute__((ext_vector_type(8))) short bf16x8;
typedef __attribute__((ext_vector_type(4))) float f32x4;
typedef __attribute__((ext_vector_type(4))) short sh4;

#define GLOBAL_AS __attribute__((address_space(1)))
#define LDS_AS    __attribute__((address_space(3)))
#define MFMA16 __builtin_amdgcn_mfma_f32_16x16x32_bf16

__device__ __forceinline__ short f2bs(float v){
    __hip_bfloat16 h = __float2bfloat16(v);
    return *reinterpret_cast<short*>(&h);
}
__device__ __forceinline__ float bs2f(short s){
    __hip_bfloat16 h = *reinterpret_cast<__hip_bfloat16*>(&s);
    return __bfloat162float(h);
}
__device__ __forceinline__ void gload16(const void* g, void* l){
    __builtin_amdgcn_global_load_lds((const GLOBAL_AS unsigned int*)g,
                                     (LDS_AS unsigned int*)l, 16, 0, 0);
}

enum { AG_ROW = 0, AG_POOL = 1, AG_FUSE = 2, AG_CONV = 3, AG_SEL3 = 4, AG_QK = 5 };
enum { EP_QKV = 0, EP_POOL = 1, EP_PVN = 7, EP_FUSE_STATS = 8, EP_SPLIT_F32 = 9, EP_SCOREP = 10 };
enum { ORD_INNER_N = 0, ORD_INNER_M = 1 };

// ------------------------------------------------------------------ utility kernels
__global__ __launch_bounds__(256) void k_zero(float* p, int n){
    int i = blockIdx.x*256 + threadIdx.x;
    if (i < n) p[i] = 0.f;
}

__global__ __launch_bounds__(256) void k_cast(const float* __restrict__ s, short* __restrict__ d, int n){
    int i = (blockIdx.x*256 + threadIdx.x)*4;
    if (i >= n) return;
    float4 v = *reinterpret_cast<const float4*>(s + i);
    sh4 o; o[0]=f2bs(v.x); o[1]=f2bs(v.y); o[2]=f2bs(v.z); o[3]=f2bs(v.w);
    *reinterpret_cast<sh4*>(d + i) = o;
}

// transpose-cast: src fp32 [R][Cc] -> dst bf16 [Cc][R]
__global__ __launch_bounds__(256) void k_tcast(const float* __restrict__ src, short* __restrict__ dst,
                                               int R, int Cc){
    __shared__ float t[32][33];
    int bx = blockIdx.x*32, by = blockIdx.y*32;
    int tx = threadIdx.x & 31, ty = threadIdx.x >> 5;
    #pragma unroll
    for (int i = 0; i < 32; i += 8)
        t[ty+i][tx] = src[(size_t)(by+ty+i)*Cc + bx+tx];
    __syncthreads();
    #pragma unroll
    for (int i = 0; i < 32; i += 8)
        dst[(size_t)(bx+ty+i)*R + by+tx] = f2bs(t[tx][ty+i]);
}

// ------------------------------------------------------------------ MFMA GEMM template
// C[m][n] = sum_k A[m][k]*Bt[n][k]; 128x128 tile, BK=32, 4 waves, single-buffer (m97)
template<int AM, int EP, int ORDER, int NX, int NY, int NZ, int NT, int KT, int KROW, int KSPLIT,
         long ASTR, long BSTR>
__global__ __launch_bounds__(256) void k_mm(const short* __restrict__ A,
                                            const short* __restrict__ Bt,
                                            const short* __restrict__ A2,
                                            const float* __restrict__ sc0,
                                            void* __restrict__ O0,
                                            void* __restrict__ O1,
                                            void* __restrict__ O2,
                                            void* __restrict__ O3){
    __shared__ short Asm[128*32];
    __shared__ short Bsm[128*32];
    const int tid = threadIdx.x, wave = tid >> 6, lane = tid & 63;

    // ---- chunked XCD swizzle (bijective) ----
    constexpr int nwg = NX*NY*NZ;
    constexpr int q8 = nwg >> 3, r8 = nwg & 7;
    int orig = blockIdx.x;
    int xcd = orig & 7, idx8 = orig >> 3;
    int wg = (xcd < r8 ? xcd*(q8+1) : r8*(q8+1) + (xcd - r8)*q8) + idx8;
    int bz = wg / (NX*NY);
    int rem = wg - bz*(NX*NY);
    int nx, my;
    if constexpr (ORDER == ORD_INNER_N){ my = rem / NX; nx = rem - my*NX; }
    else                               { nx = rem / NY; my = rem - nx*NY; }

    const int m0 = my*128, n0 = nx*128;
    const short* Ab;
    if constexpr (AM == AG_SEL3){
        const short* base = (bz < 16) ? A : (bz < 32) ? A2 : (const short*)O3;
        Ab = base + (size_t)(bz & 15)*ASTR;
    } else if constexpr (AM == AG_QK){
        Ab = A + (size_t)(bz & 15)*ASTR;
    } else {
        Ab = A + (size_t)bz*ASTR;
    }
    const short* Bb;
    if constexpr (AM == AG_QK){
        const short* bbase = (bz < 16) ? Bt : (bz < 32) ? A2 : (const short*)O3;
        Bb = bbase + (size_t)(bz & 15)*BSTR;
    } else {
        Bb = Bt + (size_t)bz*BSTR;
    }

    f32x4 acc[4][4];
    #pragma unroll
    for (int i = 0; i < 4; ++i)
        #pragma unroll
        for (int j = 0; j < 4; ++j)
            acc[i][j] = (f32x4){0.f,0.f,0.f,0.f};

    const int wm = (wave >> 1)*64, wn = (wave & 1)*64;
    const int lrow = lane & 15, lk = (lane >> 4)*8;

    for (int k0 = 0; k0 < KT; k0 += 32){
        #pragma unroll
        for (int is = 0; is < 2; ++is){
            int fl = is*256 + tid;
            int r = fl >> 2, ccol = (fl & 3)*8;
            int kk = bz*KSPLIT + k0 + ccol;
            const short* ga;
            if constexpr (AM == AG_ROW || AM == AG_SEL3 || AM == AG_QK){
                ga = Ab + (size_t)(m0 + r)*KROW + kk;
            } else if constexpr (AM == AG_POOL){
                int m = m0 + r;
                int b = m >> 12, rem2 = m & 4095, g = rem2 >> 2, qd = rem2 & 3;
                int srow = (b*64 + (g>>5)*2 + (qd>>1))*64 + (g&31)*2 + (qd&1);
                ga = Ab + (size_t)srow*KROW + kk;
            } else if constexpr (AM == AG_FUSE){
                int m = m0 + r;
                int b = m >> 10, rem2 = m & 1023, h = rem2 >> 5, w = rem2 & 31;
                const short* src = (kk < 512) ? A : A2;
                ga = src + ((size_t)(b*512 + h*16 + (w>>1))*1024 + ((w&1)<<9) + (kk & 511));
            } else { // AG_CONV
                int m = m0 + r;
                int b = m >> 10, rem2 = m & 1023, h = rem2 >> 5, w = rem2 & 31;
                int tap = kk >> 9, ic = kk & 511;
                int dh = tap/3 - 1, dw = tap - (tap/3)*3 - 1;
                int hs = h + dh, wd = w + dw;
                if (hs >= 0 && hs < 32 && wd >= 0 && wd < 32)
                    ga = A + ((size_t)((b*32 + hs)*32 + wd)*512 + ic);
                else
                    ga = A2;                 // zero page
            }
            gload16(ga, &Asm[(is*4 + wave)*512]);
            const short* gb = Bb + (size_t)(n0 + r)*KROW + kk;
            gload16(gb, &Bsm[(is*4 + wave)*512]);
        }
        __syncthreads();
        bf16x8 af[4], bfr[4];
        #pragma unroll
        for (int mi = 0; mi < 4; ++mi)
            af[mi] = *(const bf16x8*)&Asm[(wm + mi*16 + lrow)*32 + lk];
        #pragma unroll
        for (int nj = 0; nj < 4; ++nj)
            bfr[nj] = *(const bf16x8*)&Bsm[(wn + nj*16 + lrow)*32 + lk];
        #pragma unroll
        for (int mi = 0; mi < 4; ++mi)
            #pragma unroll
            for (int nj = 0; nj < 4; ++nj)
                acc[mi][nj] = MFMA16(af[mi], bfr[nj], acc[mi][nj], 0, 0, 0);
        __syncthreads();
    }

    // ---------------- epilogue: C/D layout col=lane&15, row=(lane>>4)*4+reg
    const int lg = lane >> 4;

    if constexpr (EP == EP_FUSE_STATS){
        // bf16 store + per-block BN stats (LDS reduce over the 128x128 tile -> atomics)
        float* redS = (float*)Asm;   // [128][8]
        float* redQ = (float*)Bsm;   // [128][8]
        #pragma unroll
        for (int nj = 0; nj < 4; ++nj){
            int c = n0 + wn + nj*16 + lrow;
            float bias = sc0[c];
            float s = 0.f, qq = 0.f;
            #pragma unroll
            for (int mi = 0; mi < 4; ++mi){
                int r0 = m0 + wm + mi*16 + lg*4;
                #pragma unroll
                for (int rg = 0; rg < 4; ++rg){
                    float val = acc[mi][nj][rg] + bias;
                    s += val; qq += val*val;
                    ((short*)O0)[(size_t)(r0+rg)*NT + c] = f2bs(val);
                }
            }
            int chl = wn + nj*16 + lrow;
            int slot = (wave >> 1)*4 + lg;
            redS[chl*8 + slot] = s;
            redQ[chl*8 + slot] = qq;
        }
        __syncthreads();
        if (tid < 128){
            float S = 0.f, Q = 0.f;
            #pragma unroll
            for (int k = 0; k < 8; ++k){ S += redS[tid*8 + k]; Q += redQ[tid*8 + k]; }
            atomicAdd(&((float*)O1)[n0 + tid], S);
            atomicAdd(&((float*)O2)[n0 + tid], Q);
        }
        return;
    }

    if constexpr (EP == EP_SCOREP){
        // P = exp(s*SCALE) bf16 store + row-sum partials -> atomicAdd lsum[bz][row]
        short* Pb = (short*)O0 + ((size_t)bz << 20);
        float* lsum = (float*)O1 + (size_t)bz*1024;
        #pragma unroll
        for (int mi = 0; mi < 4; ++mi){
            int r0 = m0 + wm + mi*16 + lg*4;
            float s4[4] = {0.f, 0.f, 0.f, 0.f};
            #pragma unroll
            for (int nj = 0; nj < 4; ++nj){
                int c = n0 + wn + nj*16 + lrow;
                f32x4 v = acc[mi][nj];
                #pragma unroll
                for (int rg = 0; rg < 4; ++rg){
                    float p = __expf(fminf(v[rg]*SCALE_, 80.f));
                    s4[rg] += p;
                    Pb[(size_t)(r0+rg)*NT + c] = f2bs(p);
                }
            }
            #pragma unroll
            for (int off = 1; off < 16; off <<= 1){
                #pragma unroll
                for (int rg = 0; rg < 4; ++rg) s4[rg] += __shfl_xor(s4[rg], off);
            }
            if (lrow == 0){
                #pragma unroll
                for (int rg = 0; rg < 4; ++rg) atomicAdd(&lsum[r0+rg], s4[rg]);
            }
        }
        return;
    }

    #pragma unroll
    for (int mi = 0; mi < 4; ++mi)
        #pragma unroll
        for (int nj = 0; nj < 4; ++nj){
            int c  = n0 + wn + nj*16 + lrow;
            int r0 = m0 + wm + mi*16 + lg*4;
            f32x4 v = acc[mi][nj];
            if constexpr (EP == EP_QKV){
                sh4 t4;
                #pragma unroll
                for (int rg = 0; rg < 4; ++rg){
                    short s = f2bs(v[rg]);
                    ((short*)O0)[(size_t)(r0+rg)*NT + c] = s;
                    t4[rg] = s;
                }
                int b = r0 >> 10, t = r0 & 1023;
                *reinterpret_cast<sh4*>((short*)O1 + ((size_t)(b*512 + c))*1024 + t) = t4;
            } else if constexpr (EP == EP_POOL){
                float av = 0.25f*(v[0]+v[1]+v[2]+v[3]);
                float mx = fmaxf(fmaxf(v[0],v[1]), fmaxf(v[2],v[3]));
                int g = r0 >> 2;
                int b = g >> 10, t = g & 1023;
                ((short*)O0)[(size_t)g*512 + c] = f2bs(av);
                ((short*)O2)[(size_t)g*512 + c] = f2bs(mx);
                ((short*)O1)[((size_t)(b*512 + c))*1024 + t] = f2bs(av);
                ((short*)O3)[((size_t)(b*512 + c))*1024 + t] = f2bs(mx);
            } else if constexpr (EP == EP_PVN){
                short* Ob = ((bz < 16) ? (short*)O0 : (bz < 32) ? (short*)O1 : (short*)O2)
                            + (size_t)(bz & 15)*524288;
                float sc = 1.f / sc0[(size_t)bz*1024 + c];
                #pragma unroll
                for (int rg = 0; rg < 4; ++rg)
                    Ob[(size_t)(r0+rg)*NT + c] = f2bs(v[rg]*sc);
            } else { // EP_SPLIT_F32
                float* O = (float*)O0 + (size_t)bz*((long)NTOK*NT);
                #pragma unroll
                for (int rg = 0; rg < 4; ++rg)
                    O[(size_t)(r0+rg)*NT + c] = v[rg];
            }
        }
}

// ------------------------------------------------------------------ x_prev^T = beta*avgT + (1-beta)*maxT
__global__ __launch_bounds__(256) void k_combine(const short* __restrict__ av,
                                                 const short* __restrict__ mx,
                                                 short* __restrict__ o,
                                                 const float* __restrict__ beta){
    int i = (blockIdx.x*256 + threadIdx.x)*8;
    float be = beta[0];
    bf16x8 va = *(const bf16x8*)&av[i];
    bf16x8 vm = *(const bf16x8*)&mx[i];
    bf16x8 vo;
    #pragma unroll
    for (int j = 0; j < 8; ++j)
        vo[j] = f2bs(be*bs2f(va[j]) + (1.f - be)*bs2f(vm[j]));
    *reinterpret_cast<bf16x8*>(&o[i]) = vo;
}

// ------------------------------------------------------------------ merge fp32 split-K conv partials + bias,
// write fp32 Y, accumulate BN2 stats (round-12 float2 pattern, 1024 blocks for TLP)
__global__ __launch_bounds__(256) void k_stats2(const float* __restrict__ p0,
                                                const float* __restrict__ p1,
                                                const float* __restrict__ bias,
                                                float* __restrict__ Y,
                                                float* __restrict__ sum, float* __restrict__ sumsq){
    int t = threadIdx.x, c0 = t*2, r0 = blockIdx.x*16;
    float b0 = bias[c0], b1 = bias[c0+1];
    float s0=0, s1=0, q0=0, q1=0;
    for (int r = 0; r < 16; ++r){
        size_t off = (size_t)(r0+r)*C_ + c0;
        float2 a = *reinterpret_cast<const float2*>(p0 + off);
        float2 b = *reinterpret_cast<const float2*>(p1 + off);
        float v0 = a.x + b.x + b0, v1 = a.y + b.y + b1;
        float2 ov; ov.x = v0; ov.y = v1;
        *reinterpret_cast<float2*>(Y + off) = ov;
        s0 += v0; q0 += v0*v0; s1 += v1; q1 += v1*v1;
    }
    atomicAdd(&sum[c0],   s0); atomicAdd(&sum[c0+1],   s1);
    atomicAdd(&sumsq[c0], q0); atomicAdd(&sumsq[c0+1], q1);
}

// ------------------------------------------------------------------ x2 = x + gamma*relu(BN1(fusx)), bf16 in/out, x4
__global__ __launch_bounds__(256) void k_apply1(const short* __restrict__ fusxq,
                                                const float* __restrict__ x,
                                                const float* __restrict__ sum,
                                                const float* __restrict__ sumsq,
                                                const float* __restrict__ g,
                                                const float* __restrict__ bb,
                                                const float* __restrict__ gamma,
                                                short* __restrict__ x2q){
    int i4 = (blockIdx.x*256 + threadIdx.x)*4;
    int c = i4 & (C_-1);
    sh4 f = *reinterpret_cast<const sh4*>(fusxq + i4);
    float4 xv = *reinterpret_cast<const float4*>(x + i4);
    float gm = gamma[0];
    sh4 o;
    #pragma unroll
    for (int j = 0; j < 4; ++j){
        int cj = c + j;
        float mean = sum[cj]*(1.f/NTOK);
        float var  = sumsq[cj]*(1.f/NTOK) - mean*mean;
        float t = (bs2f(f[j]) - mean)*rsqrtf(var + EPS_)*g[cj] + bb[cj];
        float xj = (j==0) ? xv.x : (j==1) ? xv.y : (j==2) ? xv.z : xv.w;
        o[j] = f2bs(xj + gm*fmaxf(t, 0.f));
    }
    *reinterpret_cast<sh4*>(x2q + i4) = o;
}

// ------------------------------------------------------------------ out = relu(BN2(y)) in place, float4
__global__ __launch_bounds__(256) void k_apply2(float* __restrict__ Y,
                                                const float* __restrict__ sum,
                                                const float* __restrict__ sumsq,
                                                const float* __restrict__ g,
                                                const float* __restrict__ bb){
    int i4 = (blockIdx.x*256 + threadIdx.x)*4;
    int c = i4 & (C_-1);
    float4 v = *reinterpret_cast<float4*>(Y + i4);
    float o[4] = {v.x, v.y, v.z, v.w};
    #pragma unroll
    for (int j = 0; j < 4; ++j){
        int cj = c + j;
        float mean = sum[cj]*(1.f/NTOK);
        float var  = sumsq[cj]*(1.f/NTOK) - mean*mean;
        float t = (o[j] - mean)*rsqrtf(var + EPS_)*g[cj] + bb[cj];
        o[j] = fmaxf(t, 0.f);
    }
    float4 ov; ov.x = o[0]; ov.y = o[1]; ov.z = o[2]; ov.w = o[3];
    *reinterpret_cast<float4*>(Y + i4) = ov;
}

// ------------------------------------------------------------------ launch
extern "C" void kernel_launch(void* const* d_in, const int* in_sizes, int n_in,
                              void* d_out, int out_size, void* d_ws, size_t ws_size,
                              hipStream_t stream){
    const float* x      = (const float*)d_in[0];
    const float* prevx  = (const float*)d_in[1];
    const float* w_prev = (const float*)d_in[2];
    const float* w_qkv  = (const float*)d_in[3];
    const float* fuse_w = (const float*)d_in[4];
    const float* fuse_b = (const float*)d_in[5];
    const float* bn1_g  = (const float*)d_in[6];
    const float* bn1_b  = (const float*)d_in[7];
    const float* out_w  = (const float*)d_in[8];
    const float* out_b  = (const float*)d_in[9];
    const float* bn2_g  = (const float*)d_in[10];
    const float* bn2_b  = (const float*)d_in[11];
    const float* gamma  = (const float*)d_in[12];
    const float* beta   = (const float*)d_in[13];
    float* out = (float*)d_out;

    char* ws8 = (char*)d_ws;
    // Phase-aliased region 0..100663296 (96 MiB):
    //   early: pxq (33.5M @0), xq (16.8M @33554432)  [dead before scorep GEMM]
    //   mid:   Pall bf16 [3][16][1024][1024]          [dead after PV GEMM]
    //   late:  cpart (2x33.6M fp32 conv split-K partials)
    short* pxq  = (short*)(ws8 + 0);
    short* xq   = (short*)(ws8 + 33554432);
    short* Pall = (short*)(ws8 + 0);
    float* cpart= (float*)(ws8 + 0);
    short* qkvT = (short*)(ws8 + 100663296);
    short* x2q  = (short*)(ws8 + 100663296);     // alias: qkvT dead after PV
    short* avgkT= (short*)(ws8 + 117440512);
    short* maxkT= (short*)(ws8 + 134217728);
    short* prevT= maxkT;                         // combine writes after PV (maxkT dead)
    short* nowT = (short*)(ws8 + 150994944);
    short* avgk = nowT;                          // pool writes, scorep reads, PV overwrites
    short* avgT = (short*)(ws8 + 167772160);
    short* maxk = avgT;                          // pool writes, scorep reads, PV overwrites
    short* maxT = (short*)(ws8 + 184549376);
    short* fusxq= (short*)(ws8 + 184549376);     // bf16 fusx, aliases maxT after combine
    short* qkv  = (short*)(ws8 + 201326592);     // dead after scorep GEMM
    short* wqT  = (short*)(ws8 + 218103808);
    short* wpT  = (short*)(ws8 + 218628096);
    short* wfT  = (short*)(ws8 + 218890240);
    short* wcT  = (short*)(ws8 + 219938816);
    float* st   = (float*)(ws8 + 224657408);     // 2048 stats + 256-float zero page + lsum (contiguous)
    short* zpg  = (short*)(ws8 + 224665600);
    float* lsum = (float*)(ws8 + 224666624);     // 48*1024 f32 row sums
    float *s1sum = st, *s1sq = st + 512, *s2sum = st + 1024, *s2sq = st + 1536;

    dim3 blk(256);
    // zero: stats (2048) + zero page (256) + lsum (49152) — contiguous 51456 floats
    k_zero<<<201, blk, 0, stream>>>(st, 51456);
    // casts / weight transposes
    k_cast<<<8192, blk, 0, stream>>>(x, xq, 8388608);
    k_cast<<<256,  blk, 0, stream>>>(w_qkv, wqT, 262144);
    k_cast<<<128,  blk, 0, stream>>>(w_prev, wpT, 131072);
    k_tcast<<<dim3(16, 32),  blk, 0, stream>>>(fuse_w, wfT, 1024, 512);
    k_tcast<<<dim3(16, 144), blk, 0, stream>>>(out_w, wcT, 4608, 512);
    k_cast<<<16384, blk, 0, stream>>>(prevx, pxq, 16777216);

    // qkv = x @ w_qkv^T  (row-major + transposed out)
    k_mm<AG_ROW, EP_QKV, ORD_INNER_N, 4, 128, 1, 512, 512, 512, 0, 0L, 0L>
        <<<512, blk, 0, stream>>>(xq, wqT, nullptr, nullptr,
                                  qkv, qkvT, nullptr, nullptr);
    // prev qkv + fused 2x2 pooling (avgk/maxk row-major, avgkT/maxkT transposed)
    k_mm<AG_POOL, EP_POOL, ORD_INNER_N, 4, 512, 1, 512, 256, 256, 0, 0L, 0L>
        <<<2048, blk, 0, stream>>>(pxq, wpT, nullptr, nullptr,
                                   avgk, avgkT, maxk, maxkT);
    // scores + no-max softmax as batched GEMM: P = exp(Q.K^T*SCALE) bf16, row sums -> lsum
    k_mm<AG_QK, EP_SCOREP, ORD_INNER_M, 8, 8, 48, 1024, 512, 512, 0, 524288L, 524288L>
        <<<3072, blk, 0, stream>>>(qkv, qkv, avgk, nullptr,
                                   Pall, lsum, nullptr, maxk);
    // PV as batched GEMM: O^T[ch][tok] = sum_kv V^T[ch][kv] * P[tok][kv], scaled by 1/lsum[tok]
    k_mm<AG_SEL3, EP_PVN, ORD_INNER_M, 8, 4, 48, 1024, 1024, 1024, 0, 524288L, 1048576L>
        <<<1536, blk, 0, stream>>>(qkvT, Pall, avgkT, lsum,
                                   nowT, avgT, maxT, maxkT);
    // x_prev^T = beta*avgT + (1-beta)*maxT
    k_combine<<<4096, blk, 0, stream>>>(avgT, maxT, prevT, beta);
    // fuse 1x1 + bias + BN1 stats fused into epilogue; fusx stored bf16
    k_mm<AG_FUSE, EP_FUSE_STATS, ORD_INNER_N, 4, 128, 1, 512, 1024, 1024, 0, 0L, 0L>
        <<<512, blk, 0, stream>>>(nowT, wfT, prevT, fuse_b,
                                  fusxq, s1sum, s1sq, nullptr);
    k_apply1<<<8192, blk, 0, stream>>>(fusxq, x, s1sum, s1sq, bn1_g, bn1_b, gamma, x2q);
    // 3x3 conv (implicit GEMM, split-K x2, fp32 partials) + merge/stats + BN2
    k_mm<AG_CONV, EP_SPLIT_F32, ORD_INNER_N, 4, 128, 2, 512, 2304, 4608, 2304, 0L, 0L>
        <<<1024, blk, 0, stream>>>(x2q, wcT, zpg, nullptr,
                                   cpart, nullptr, nullptr, nullptr);
    k_stats2<<<1024, blk, 0, stream>>>(cpart, cpart + (size_t)NTOK*C_, out_b, out, s2sum, s2sq);
    k_apply2<<<8192, blk, 0, stream>>>(out, s2sum, s2sq, bn2_g, bn2_b);
}

// Round 16
// 472.537 us; speedup vs baseline: 1.3326x; 1.0319x over previous
//
#include <hip/hip_runtime.h>
#include <hip/hip_bf16.h>

#define B_   16
#define C_   512
#define N_   1024
#define NTOK 16384
#define SCALE_ 0.17677669529663687f
#define EPS_ 1e-5f

typedef __attribute__((ext_vector_type(8))) short bf16x8;
typedef __attribute__((ext_vector_type(4))) float f32x4;
typedef __attribute__((ext_vector_type(4))) short sh4;

#define GLOBAL_AS __attribute__((address_space(1)))
#define LDS_AS    __attribute__((address_space(3)))
#define MFMA16 __builtin_amdgcn_mfma_f32_16x16x32_bf16

__device__ __forceinline__ short f2bs(float v){
    __hip_bfloat16 h = __float2bfloat16(v);
    return *reinterpret_cast<short*>(&h);
}
__device__ __forceinline__ float bs2f(short s){
    __hip_bfloat16 h = *reinterpret_cast<__hip_bfloat16*>(&s);
    return __bfloat162float(h);
}
__device__ __forceinline__ void gload16(const void* g, void* l){
    __builtin_amdgcn_global_load_lds((const GLOBAL_AS unsigned int*)g,
                                     (LDS_AS unsigned int*)l, 16, 0, 0);
}

enum { AG_ROW = 0, AG_POOL = 1, AG_FUSE = 2, AG_CONV = 3, AG_SEL3 = 4, AG_QK = 5 };
enum { EP_QKV = 0, EP_POOL = 1, EP_PVN = 7, EP_FUSE_STATS = 8, EP_SPLIT_F32 = 9, EP_SCOREP = 10 };
enum { ORD_INNER_N = 0, ORD_INNER_M = 1 };

// ------------------------------------------------------------------ utility kernels
__global__ __launch_bounds__(256) void k_zero(float* p, int n){
    int i = blockIdx.x*256 + threadIdx.x;
    if (i < n) p[i] = 0.f;
}

__global__ __launch_bounds__(256) void k_cast(const float* __restrict__ s, short* __restrict__ d, int n){
    int i = (blockIdx.x*256 + threadIdx.x)*4;
    if (i >= n) return;
    float4 v = *reinterpret_cast<const float4*>(s + i);
    sh4 o; o[0]=f2bs(v.x); o[1]=f2bs(v.y); o[2]=f2bs(v.z); o[3]=f2bs(v.w);
    *reinterpret_cast<sh4*>(d + i) = o;
}

// transpose-cast: src fp32 [R][Cc] -> dst bf16 [Cc][R]
__global__ __launch_bounds__(256) void k_tcast(const float* __restrict__ src, short* __restrict__ dst,
                                               int R, int Cc){
    __shared__ float t[32][33];
    int bx = blockIdx.x*32, by = blockIdx.y*32;
    int tx = threadIdx.x & 31, ty = threadIdx.x >> 5;
    #pragma unroll
    for (int i = 0; i < 32; i += 8)
        t[ty+i][tx] = src[(size_t)(by+ty+i)*Cc + bx+tx];
    __syncthreads();
    #pragma unroll
    for (int i = 0; i < 32; i += 8)
        dst[(size_t)(bx+ty+i)*R + by+tx] = f2bs(t[tx][ty+i]);
}

// ------------------------------------------------------------------ MFMA GEMM template
// C[m][n] = sum_k A[m][k]*Bt[n][k]; 128x128 tile, BK=32, 4 waves, single-buffer (m97)
template<int AM, int EP, int ORDER, int NX, int NY, int NZ, int NT, int KT, int KROW, int KSPLIT,
         long ASTR, long BSTR>
__global__ __launch_bounds__(256) void k_mm(const short* __restrict__ A,
                                            const short* __restrict__ Bt,
                                            const short* __restrict__ A2,
                                            const float* __restrict__ sc0,
                                            void* __restrict__ O0,
                                            void* __restrict__ O1,
                                            void* __restrict__ O2,
                                            void* __restrict__ O3){
    __shared__ short Asm[128*32];
    __shared__ short Bsm[128*32];
    const int tid = threadIdx.x, wave = tid >> 6, lane = tid & 63;

    // ---- chunked XCD swizzle (bijective) ----
    constexpr int nwg = NX*NY*NZ;
    constexpr int q8 = nwg >> 3, r8 = nwg & 7;
    int orig = blockIdx.x;
    int xcd = orig & 7, idx8 = orig >> 3;
    int wg = (xcd < r8 ? xcd*(q8+1) : r8*(q8+1) + (xcd - r8)*q8) + idx8;
    int bz = wg / (NX*NY);
    int rem = wg - bz*(NX*NY);
    int nx, my;
    if constexpr (ORDER == ORD_INNER_N){ my = rem / NX; nx = rem - my*NX; }
    else                               { nx = rem / NY; my = rem - nx*NY; }

    const int m0 = my*128, n0 = nx*128;
    const short* Ab;
    if constexpr (AM == AG_SEL3){
        const short* base = (bz < 16) ? A : (bz < 32) ? A2 : (const short*)O3;
        Ab = base + (size_t)(bz & 15)*ASTR;
    } else if constexpr (AM == AG_QK){
        Ab = A + (size_t)(bz & 15)*ASTR;
    } else {
        Ab = A + (size_t)bz*ASTR;
    }
    const short* Bb;
    if constexpr (AM == AG_QK){
        const short* bbase = (bz < 16) ? Bt : (bz < 32) ? A2 : (const short*)O3;
        Bb = bbase + (size_t)(bz & 15)*BSTR;
    } else {
        Bb = Bt + (size_t)bz*BSTR;
    }

    f32x4 acc[4][4];
    #pragma unroll
    for (int i = 0; i < 4; ++i)
        #pragma unroll
        for (int j = 0; j < 4; ++j)
            acc[i][j] = (f32x4){0.f,0.f,0.f,0.f};

    const int wm = (wave >> 1)*64, wn = (wave & 1)*64;
    const int lrow = lane & 15, lk = (lane >> 4)*8;

    for (int k0 = 0; k0 < KT; k0 += 32){
        #pragma unroll
        for (int is = 0; is < 2; ++is){
            int fl = is*256 + tid;
            int r = fl >> 2, ccol = (fl & 3)*8;
            int kk = bz*KSPLIT + k0 + ccol;
            const short* ga;
            if constexpr (AM == AG_ROW || AM == AG_SEL3 || AM == AG_QK){
                ga = Ab + (size_t)(m0 + r)*KROW + kk;
            } else if constexpr (AM == AG_POOL){
                int m = m0 + r;
                int b = m >> 12, rem2 = m & 4095, g = rem2 >> 2, qd = rem2 & 3;
                int srow = (b*64 + (g>>5)*2 + (qd>>1))*64 + (g&31)*2 + (qd&1);
                ga = Ab + (size_t)srow*KROW + kk;
            } else if constexpr (AM == AG_FUSE){
                int m = m0 + r;
                int b = m >> 10, rem2 = m & 1023, h = rem2 >> 5, w = rem2 & 31;
                const short* src = (kk < 512) ? A : A2;
                ga = src + ((size_t)(b*512 + h*16 + (w>>1))*1024 + ((w&1)<<9) + (kk & 511));
            } else { // AG_CONV
                int m = m0 + r;
                int b = m >> 10, rem2 = m & 1023, h = rem2 >> 5, w = rem2 & 31;
                int tap = kk >> 9, ic = kk & 511;
                int dh = tap/3 - 1, dw = tap - (tap/3)*3 - 1;
                int hs = h + dh, wd = w + dw;
                if (hs >= 0 && hs < 32 && wd >= 0 && wd < 32)
                    ga = A + ((size_t)((b*32 + hs)*32 + wd)*512 + ic);
                else
                    ga = A2;                 // zero page
            }
            gload16(ga, &Asm[(is*4 + wave)*512]);
            const short* gb = Bb + (size_t)(n0 + r)*KROW + kk;
            gload16(gb, &Bsm[(is*4 + wave)*512]);
        }
        __syncthreads();
        bf16x8 af[4], bfr[4];
        #pragma unroll
        for (int mi = 0; mi < 4; ++mi)
            af[mi] = *(const bf16x8*)&Asm[(wm + mi*16 + lrow)*32 + lk];
        #pragma unroll
        for (int nj = 0; nj < 4; ++nj)
            bfr[nj] = *(const bf16x8*)&Bsm[(wn + nj*16 + lrow)*32 + lk];
        #pragma unroll
        for (int mi = 0; mi < 4; ++mi)
            #pragma unroll
            for (int nj = 0; nj < 4; ++nj)
                acc[mi][nj] = MFMA16(af[mi], bfr[nj], acc[mi][nj], 0, 0, 0);
        __syncthreads();
    }

    // ---------------- epilogue: C/D layout col=lane&15, row=(lane>>4)*4+reg
    const int lg = lane >> 4;

    if constexpr (EP == EP_FUSE_STATS){
        // bf16 store + per-block BN stats (LDS reduce over the 128x128 tile -> atomics)
        float* redS = (float*)Asm;   // [128][8]
        float* redQ = (float*)Bsm;   // [128][8]
        #pragma unroll
        for (int nj = 0; nj < 4; ++nj){
            int c = n0 + wn + nj*16 + lrow;
            float bias = sc0[c];
            float s = 0.f, qq = 0.f;
            #pragma unroll
            for (int mi = 0; mi < 4; ++mi){
                int r0 = m0 + wm + mi*16 + lg*4;
                #pragma unroll
                for (int rg = 0; rg < 4; ++rg){
                    float val = acc[mi][nj][rg] + bias;
                    s += val; qq += val*val;
                    ((short*)O0)[(size_t)(r0+rg)*NT + c] = f2bs(val);
                }
            }
            int chl = wn + nj*16 + lrow;
            int slot = (wave >> 1)*4 + lg;
            redS[chl*8 + slot] = s;
            redQ[chl*8 + slot] = qq;
        }
        __syncthreads();
        if (tid < 128){
            float S = 0.f, Q = 0.f;
            #pragma unroll
            for (int k = 0; k < 8; ++k){ S += redS[tid*8 + k]; Q += redQ[tid*8 + k]; }
            atomicAdd(&((float*)O1)[n0 + tid], S);
            atomicAdd(&((float*)O2)[n0 + tid], Q);
        }
        return;
    }

    if constexpr (EP == EP_SCOREP){
        // P = exp(s*SCALE) bf16 store + row-sum partials -> atomicAdd lsum[bz][row]
        short* Pb = (short*)O0 + ((size_t)bz << 20);
        float* lsum = (float*)O1 + (size_t)bz*1024;
        #pragma unroll
        for (int mi = 0; mi < 4; ++mi){
            int r0 = m0 + wm + mi*16 + lg*4;
            float s4[4] = {0.f, 0.f, 0.f, 0.f};
            #pragma unroll
            for (int nj = 0; nj < 4; ++nj){
                int c = n0 + wn + nj*16 + lrow;
                f32x4 v = acc[mi][nj];
                #pragma unroll
                for (int rg = 0; rg < 4; ++rg){
                    float p = __expf(fminf(v[rg]*SCALE_, 80.f));
                    s4[rg] += p;
                    Pb[(size_t)(r0+rg)*NT + c] = f2bs(p);
                }
            }
            #pragma unroll
            for (int off = 1; off < 16; off <<= 1){
                #pragma unroll
                for (int rg = 0; rg < 4; ++rg) s4[rg] += __shfl_xor(s4[rg], off);
            }
            if (lrow == 0){
                #pragma unroll
                for (int rg = 0; rg < 4; ++rg) atomicAdd(&lsum[r0+rg], s4[rg]);
            }
        }
        return;
    }

    #pragma unroll
    for (int mi = 0; mi < 4; ++mi)
        #pragma unroll
        for (int nj = 0; nj < 4; ++nj){
            int c  = n0 + wn + nj*16 + lrow;
            int r0 = m0 + wm + mi*16 + lg*4;
            f32x4 v = acc[mi][nj];
            if constexpr (EP == EP_QKV){
                sh4 t4;
                #pragma unroll
                for (int rg = 0; rg < 4; ++rg){
                    short s = f2bs(v[rg]);
                    ((short*)O0)[(size_t)(r0+rg)*NT + c] = s;
                    t4[rg] = s;
                }
                int b = r0 >> 10, t = r0 & 1023;
                *reinterpret_cast<sh4*>((short*)O1 + ((size_t)(b*512 + c))*1024 + t) = t4;
            } else if constexpr (EP == EP_POOL){
                float av = 0.25f*(v[0]+v[1]+v[2]+v[3]);
                float mx = fmaxf(fmaxf(v[0],v[1]), fmaxf(v[2],v[3]));
                int g = r0 >> 2;
                int b = g >> 10, t = g & 1023;
                ((short*)O0)[(size_t)g*512 + c] = f2bs(av);
                ((short*)O2)[(size_t)g*512 + c] = f2bs(mx);
                ((short*)O1)[((size_t)(b*512 + c))*1024 + t] = f2bs(av);
                ((short*)O3)[((size_t)(b*512 + c))*1024 + t] = f2bs(mx);
            } else if constexpr (EP == EP_PVN){
                short* Ob = ((bz < 16) ? (short*)O0 : (bz < 32) ? (short*)O1 : (short*)O2)
                            + (size_t)(bz & 15)*524288;
                float sc = 1.f / sc0[(size_t)bz*1024 + c];
                #pragma unroll
                for (int rg = 0; rg < 4; ++rg)
                    Ob[(size_t)(r0+rg)*NT + c] = f2bs(v[rg]*sc);
            } else { // EP_SPLIT_F32
                float* O = (float*)O0 + (size_t)bz*((long)NTOK*NT);
                #pragma unroll
                for (int rg = 0; rg < 4; ++rg)
                    O[(size_t)(r0+rg)*NT + c] = v[rg];
            }
        }
}

// ------------------------------------------------------------------ x_prev^T = beta*avgT + (1-beta)*maxT
__global__ __launch_bounds__(256) void k_combine(const short* __restrict__ av,
                                                 const short* __restrict__ mx,
                                                 short* __restrict__ o,
                                                 const float* __restrict__ beta){
    int i = (blockIdx.x*256 + threadIdx.x)*8;
    float be = beta[0];
    bf16x8 va = *(const bf16x8*)&av[i];
    bf16x8 vm = *(const bf16x8*)&mx[i];
    bf16x8 vo;
    #pragma unroll
    for (int j = 0; j < 8; ++j)
        vo[j] = f2bs(be*bs2f(va[j]) + (1.f - be)*bs2f(vm[j]));
    *reinterpret_cast<bf16x8*>(&o[i]) = vo;
}

// ------------------------------------------------------------------ merge fp32 split-K conv partials + bias,
// write fp32 Y, accumulate BN2 stats (round-12 proven config: 512 blocks x 32 rows, float2)
__global__ __launch_bounds__(256) void k_stats2(const float* __restrict__ p0,
                                                const float* __restrict__ p1,
                                                const float* __restrict__ bias,
                                                float* __restrict__ Y,
                                                float* __restrict__ sum, float* __restrict__ sumsq){
    int t = threadIdx.x, c0 = t*2, r0 = blockIdx.x*32;
    float b0 = bias[c0], b1 = bias[c0+1];
    float s0=0, s1=0, q0=0, q1=0;
    for (int r = 0; r < 32; ++r){
        size_t off = (size_t)(r0+r)*C_ + c0;
        float2 a = *reinterpret_cast<const float2*>(p0 + off);
        float2 b = *reinterpret_cast<const float2*>(p1 + off);
        float v0 = a.x + b.x + b0, v1 = a.y + b.y + b1;
        float2 ov; ov.x = v0; ov.y = v1;
        *reinterpret_cast<float2*>(Y + off) = ov;
        s0 += v0; q0 += v0*v0; s1 += v1; q1 += v1*v1;
    }
    atomicAdd(&sum[c0],   s0); atomicAdd(&sum[c0+1],   s1);
    atomicAdd(&sumsq[c0], q0); atomicAdd(&sumsq[c0+1], q1);
}

// ------------------------------------------------------------------ x2 = x + gamma*relu(BN1(fusx)), bf16 in/out, x4
__global__ __launch_bounds__(256) void k_apply1(const short* __restrict__ fusxq,
                                                const float* __restrict__ x,
                                                const float* __restrict__ sum,
                                                const float* __restrict__ sumsq,
                                                const float* __restrict__ g,
                                                const float* __restrict__ bb,
                                                const float* __restrict__ gamma,
                                                short* __restrict__ x2q){
    int i4 = (blockIdx.x*256 + threadIdx.x)*4;
    int c = i4 & (C_-1);
    sh4 f = *reinterpret_cast<const sh4*>(fusxq + i4);
    float4 xv = *reinterpret_cast<const float4*>(x + i4);
    float gm = gamma[0];
    sh4 o;
    #pragma unroll
    for (int j = 0; j < 4; ++j){
        int cj = c + j;
        float mean = sum[cj]*(1.f/NTOK);
        float var  = sumsq[cj]*(1.f/NTOK) - mean*mean;
        float t = (bs2f(f[j]) - mean)*rsqrtf(var + EPS_)*g[cj] + bb[cj];
        float xj = (j==0) ? xv.x : (j==1) ? xv.y : (j==2) ? xv.z : xv.w;
        o[j] = f2bs(xj + gm*fmaxf(t, 0.f));
    }
    *reinterpret_cast<sh4*>(x2q + i4) = o;
}

// ------------------------------------------------------------------ out = relu(BN2(y)) in place, float4
__global__ __launch_bounds__(256) void k_apply2(float* __restrict__ Y,
                                                const float* __restrict__ sum,
                                                const float* __restrict__ sumsq,
                                                const float* __restrict__ g,
                                                const float* __restrict__ bb){
    int i4 = (blockIdx.x*256 + threadIdx.x)*4;
    int c = i4 & (C_-1);
    float4 v = *reinterpret_cast<float4*>(Y + i4);
    float o[4] = {v.x, v.y, v.z, v.w};
    #pragma unroll
    for (int j = 0; j < 4; ++j){
        int cj = c + j;
        float mean = sum[cj]*(1.f/NTOK);
        float var  = sumsq[cj]*(1.f/NTOK) - mean*mean;
        float t = (o[j] - mean)*rsqrtf(var + EPS_)*g[cj] + bb[cj];
        o[j] = fmaxf(t, 0.f);
    }
    float4 ov; ov.x = o[0]; ov.y = o[1]; ov.z = o[2]; ov.w = o[3];
    *reinterpret_cast<float4*>(Y + i4) = ov;
}

// ------------------------------------------------------------------ launch
extern "C" void kernel_launch(void* const* d_in, const int* in_sizes, int n_in,
                              void* d_out, int out_size, void* d_ws, size_t ws_size,
                              hipStream_t stream){
    const float* x      = (const float*)d_in[0];
    const float* prevx  = (const float*)d_in[1];
    const float* w_prev = (const float*)d_in[2];
    const float* w_qkv  = (const float*)d_in[3];
    const float* fuse_w = (const float*)d_in[4];
    const float* fuse_b = (const float*)d_in[5];
    const float* bn1_g  = (const float*)d_in[6];
    const float* bn1_b  = (const float*)d_in[7];
    const float* out_w  = (const float*)d_in[8];
    const float* out_b  = (const float*)d_in[9];
    const float* bn2_g  = (const float*)d_in[10];
    const float* bn2_b  = (const float*)d_in[11];
    const float* gamma  = (const float*)d_in[12];
    const float* beta   = (const float*)d_in[13];
    float* out = (float*)d_out;

    char* ws8 = (char*)d_ws;
    // Phase-aliased region 0..100663296 (96 MiB):
    //   early: pxq (33.5M @0), xq (16.8M @33554432)  [dead before scorep GEMM]
    //   mid:   Pall bf16 [3][16][1024][1024]          [dead after PV GEMM]
    //   late:  cpart (2x33.6M fp32 conv split-K partials)
    short* pxq  = (short*)(ws8 + 0);
    short* xq   = (short*)(ws8 + 33554432);
    short* Pall = (short*)(ws8 + 0);
    float* cpart= (float*)(ws8 + 0);
    short* qkvT = (short*)(ws8 + 100663296);
    short* x2q  = (short*)(ws8 + 100663296);     // alias: qkvT dead after PV
    short* avgkT= (short*)(ws8 + 117440512);
    short* maxkT= (short*)(ws8 + 134217728);
    short* prevT= maxkT;                         // combine writes after PV (maxkT dead)
    short* nowT = (short*)(ws8 + 150994944);
    short* avgk = nowT;                          // pool writes, scorep reads, PV overwrites
    short* avgT = (short*)(ws8 + 167772160);
    short* maxk = avgT;                          // pool writes, scorep reads, PV overwrites
    short* maxT = (short*)(ws8 + 184549376);
    short* fusxq= (short*)(ws8 + 184549376);     // bf16 fusx, aliases maxT after combine
    short* qkv  = (short*)(ws8 + 201326592);     // dead after scorep GEMM
    short* wqT  = (short*)(ws8 + 218103808);
    short* wpT  = (short*)(ws8 + 218628096);
    short* wfT  = (short*)(ws8 + 218890240);
    short* wcT  = (short*)(ws8 + 219938816);
    float* st   = (float*)(ws8 + 224657408);     // 2048 stats + 256-float zero page + lsum (contiguous)
    short* zpg  = (short*)(ws8 + 224665600);
    float* lsum = (float*)(ws8 + 224666624);     // 48*1024 f32 row sums
    float *s1sum = st, *s1sq = st + 512, *s2sum = st + 1024, *s2sq = st + 1536;

    dim3 blk(256);
    // zero: stats (2048) + zero page (256) + lsum (49152) — contiguous 51456 floats
    k_zero<<<201, blk, 0, stream>>>(st, 51456);
    // casts / weight transposes
    k_cast<<<8192, blk, 0, stream>>>(x, xq, 8388608);
    k_cast<<<256,  blk, 0, stream>>>(w_qkv, wqT, 262144);
    k_cast<<<128,  blk, 0, stream>>>(w_prev, wpT, 131072);
    k_tcast<<<dim3(16, 32),  blk, 0, stream>>>(fuse_w, wfT, 1024, 512);
    k_tcast<<<dim3(16, 144), blk, 0, stream>>>(out_w, wcT, 4608, 512);
    k_cast<<<16384, blk, 0, stream>>>(prevx, pxq, 16777216);

    // qkv = x @ w_qkv^T  (row-major + transposed out)
    k_mm<AG_ROW, EP_QKV, ORD_INNER_N, 4, 128, 1, 512, 512, 512, 0, 0L, 0L>
        <<<512, blk, 0, stream>>>(xq, wqT, nullptr, nullptr,
                                  qkv, qkvT, nullptr, nullptr);
    // prev qkv + fused 2x2 pooling (avgk/maxk row-major, avgkT/maxkT transposed)
    k_mm<AG_POOL, EP_POOL, ORD_INNER_N, 4, 512, 1, 512, 256, 256, 0, 0L, 0L>
        <<<2048, blk, 0, stream>>>(pxq, wpT, nullptr, nullptr,
                                   avgk, avgkT, maxk, maxkT);
    // scores + no-max softmax as batched GEMM: P = exp(Q.K^T*SCALE) bf16, row sums -> lsum
    k_mm<AG_QK, EP_SCOREP, ORD_INNER_M, 8, 8, 48, 1024, 512, 512, 0, 524288L, 524288L>
        <<<3072, blk, 0, stream>>>(qkv, qkv, avgk, nullptr,
                                   Pall, lsum, nullptr, maxk);
    // PV as batched GEMM: O^T[ch][tok] = sum_kv V^T[ch][kv] * P[tok][kv], scaled by 1/lsum[tok]
    k_mm<AG_SEL3, EP_PVN, ORD_INNER_M, 8, 4, 48, 1024, 1024, 1024, 0, 524288L, 1048576L>
        <<<1536, blk, 0, stream>>>(qkvT, Pall, avgkT, lsum,
                                   nowT, avgT, maxT, maxkT);
    // x_prev^T = beta*avgT + (1-beta)*maxT
    k_combine<<<4096, blk, 0, stream>>>(avgT, maxT, prevT, beta);
    // fuse 1x1 + bias + BN1 stats fused into epilogue; fusx stored bf16
    k_mm<AG_FUSE, EP_FUSE_STATS, ORD_INNER_N, 4, 128, 1, 512, 1024, 1024, 0, 0L, 0L>
        <<<512, blk, 0, stream>>>(nowT, wfT, prevT, fuse_b,
                                  fusxq, s1sum, s1sq, nullptr);
    k_apply1<<<8192, blk, 0, stream>>>(fusxq, x, s1sum, s1sq, bn1_g, bn1_b, gamma, x2q);
    // 3x3 conv (implicit GEMM, split-K x2, fp32 partials) + merge/stats + BN2
    k_mm<AG_CONV, EP_SPLIT_F32, ORD_INNER_N, 4, 128, 2, 512, 2304, 4608, 2304, 0L, 0L>
        <<<1024, blk, 0, stream>>>(x2q, wcT, zpg, nullptr,
                                   cpart, nullptr, nullptr, nullptr);
    k_stats2<<<512, blk, 0, stream>>>(cpart, cpart + (size_t)NTOK*C_, out_b, out, s2sum, s2sq);
    k_apply2<<<8192, blk, 0, stream>>>(out, s2sum, s2sq, bn2_g, bn2_b);
}